// Round 8
// baseline (234.151 us; speedup 1.0000x reference)
//
#include <hip/hip_runtime.h>
#include <math.h>
#include <stdint.h>

#define DEV static __device__ __forceinline__
typedef unsigned short u16;

constexpr int D = 256;
constexpr int S = 4096;
constexpr int QSTR = 272;            // Qb row: 256 data + 12 bias-ext + 4 zero
constexpr int KT_TILE = 8960;        // u16: 32 rows x 280
constexpr int VT_TILE = 10240;       // u16: 256 e-rows x 40 (padded for LDS bank spread)

typedef short bf16x8 __attribute__((ext_vector_type(8)));
typedef float f32x16 __attribute__((ext_vector_type(16)));

// RNE f32->bf16 via native convert (v_cvt_pk_bf16_f32)
DEV u16 f2bf(float f){ __bf16 b = (__bf16)f; return __builtin_bit_cast(u16, b); }
DEV float bf2f(u16 h){ return __uint_as_float(((unsigned)h)<<16); }
DEV int packbf(float lo, float hi){ return (int)((((unsigned)f2bf(hi)) << 16) | (unsigned)f2bf(lo)); }
DEV float bfsum2(int d){
  return __uint_as_float(((unsigned)d)<<16) + __uint_as_float(((unsigned)d) & 0xffff0000u);
}
DEV float ex2(float x){ return __builtin_amdgcn_exp2f(x); }   // v_exp_f32 (2^x native)
DEV void gl_lds16(const u16* g, u16* l) {
  __builtin_amdgcn_global_load_lds(
      (const __attribute__((address_space(1))) unsigned int*)g,
      (__attribute__((address_space(3))) unsigned int*)l, 16, 0, 0);
}

// one half (8 scores) of a tile's softmax -> one P^T B-fragment + running l.
// Split in two so pf1's VALU can overlap the pf0-consuming MFMA stream (the
// combined version forced ALL softmax before the 2nd MFMA of the interleave).
DEV bf16x8 softmax_half(const f32x16& s, int s2, int h, float& l_acc) {
  float e0 = ex2(s[8*s2+0]), e1 = ex2(s[8*s2+1]);
  float e2 = ex2(s[8*s2+2]), e3 = ex2(s[8*s2+3]);
  float e4 = ex2(s[8*s2+4]), e5 = ex2(s[8*s2+5]);
  float e6 = ex2(s[8*s2+6]), e7 = ex2(s[8*s2+7]);
  int P0d0 = packbf(e0, e1), P0d1 = packbf(e2, e3);
  int P1d0 = packbf(e4, e5), P1d1 = packbf(e6, e7);
  // l sums the bf16-ROUNDED p so normalization cancels rounding bias
  l_acc += bfsum2(P0d0) + bfsum2(P0d1) + bfsum2(P1d0) + bfsum2(P1d1);
  int s0 = h ? P0d0 : P1d0;
  int s1 = h ? P0d1 : P1d1;
  int r0 = __shfl_xor(s0, 32, 64);
  int r1 = __shfl_xor(s1, 32, 64);
  union { int d[4]; bf16x8 v; } u;
  u.d[0] = h ? r0 : P0d0;
  u.d[1] = h ? r1 : P0d1;
  u.d[2] = h ? P1d0 : r0;
  u.d[3] = h ? P1d1 : r1;
  return u.v;
}

// ---------------- prep: hi/lo split (interleaved layouts), bias-ext cols, zero Lacc -----
__global__ __launch_bounds__(256) void msp_prep(
    const float* __restrict__ x, const float* __restrict__ Wq,
    const float* __restrict__ Wk, const float* __restrict__ Wv,
    const float* __restrict__ beta,
    u16* __restrict__ xc, u16* __restrict__ Wc,
    u16* __restrict__ Qb, u16* __restrict__ Kt,
    float* __restrict__ Lacc)
{
  const int blk = blockIdx.x, tid = threadIdx.x;
  if (blk < 2048) {                       // xc[row][0..255]=hi, [256..511]=lo
    int row = blk*8 + (tid>>5);
    int col = (tid&31)*8;
    const float* p = x + (size_t)row*256 + col;
    union { u16 s[8]; uint4 v; } hh, ll;
    #pragma unroll
    for (int i=0;i<8;++i){ float v = p[i]; u16 h2 = f2bf(v); hh.s[i]=h2; ll.s[i]=f2bf(v - bf2f(h2)); }
    *(uint4*)(xc + (size_t)row*512 + col)       = hh.v;
    *(uint4*)(xc + (size_t)row*512 + 256 + col) = ll.v;
  } else if (blk < 2144) {                // Wc rows: [0,256)=Wq*log2e/16, [256,512)=Wk, [512,768)=Wv
    int q = blk - 2048;                   // 96 blocks
    int mat = q >> 5;
    int idx = (q & 31)*2048 + tid*8;      // 0..65535
    int o = idx >> 8, cc = idx & 255;
    const float* W = mat==0 ? Wq : (mat==1 ? Wk : Wv);
    float sc = (mat==0) ? 0.09016844005556021f : 1.0f;   // (1/16)*log2(e) folded on Q side
    const float* p = W + (size_t)o*256 + cc;
    union { u16 s[8]; uint4 v; } hh, ll;
    #pragma unroll
    for (int i=0;i<8;++i){ float v = p[i]*sc; u16 h2 = f2bf(v); hh.s[i]=h2; ll.s[i]=f2bf(v - bf2f(h2)); }
    *(uint4*)(Wc + (size_t)(mat*256 + o)*512 + cc)       = hh.v;
    *(uint4*)(Wc + (size_t)(mat*256 + o)*512 + 256 + cc) = ll.v;
  } else if (blk < 2208) {                // bias-ext cols (64 blocks)
    int row = (blk - 2144)*256 + tid;     // b*4096 + s
    int s = row & (S-1);
    int bb = row >> 12;
    constexpr float L2E = 1.4426950408889634f;
    float b0 = beta[0]*L2E, b1 = beta[1]*L2E;   // exp2-domain: log2e on Q side
    int i24 = s % 24, i720 = s % 720;
    float t0 = (float)i24  * 0.26179938779914944f;    // 2pi/24
    float t1 = (float)i720 * 0.008726646259971648f;   // 2pi/720
    float c0 = cosf(t0), s0 = sinf(t0), c1 = cosf(t1), s1 = sinf(t1);
    float qv[4] = {b0*c0, b0*s0, b1*c1, b1*s1};   // beta folded on Q side
    float kv[4] = {c0, s0, c1, s1};
    u16* qp = Qb + (size_t)row*QSTR + 256;
    u16* kp = Kt + (size_t)(bb*128 + (s>>5))*KT_TILE + (s&31)*280 + 256;
    #pragma unroll
    for (int n=0;n<4;++n){
      u16 uh = f2bf(qv[n]); u16 ul = f2bf(qv[n]-bf2f(uh));
      u16 vh = f2bf(kv[n]); u16 vl = f2bf(kv[n]-bf2f(vh));
      // dot over triplet = uh*vh + uh*vl + ul*vh ~= u*v (drops ul*vl <= 2^-18)
      qp[n*3+0]=uh; qp[n*3+1]=uh; qp[n*3+2]=ul;
      kp[n*3+0]=vh; kp[n*3+1]=vl; kp[n*3+2]=vh;
    }
    #pragma unroll
    for (int c=12;c<16;++c){ qp[c]=0; kp[c]=0; }
  } else {                                // zero Lacc (16384 f32)
    float4* p = (float4*)Lacc;
    float4 z = {0.f,0.f,0.f,0.f};
    #pragma unroll
    for (int c=0;c<16;++c) p[tid + c*256] = z;
  }
}

// ---------------- fused projection GEMM: C[16384x768] = xc . Wc^T, route Q/K/V ----------------
__global__ __launch_bounds__(256, 2) void msp_proj(
    const u16* __restrict__ xc, const u16* __restrict__ Wc,
    const float* __restrict__ bq, const float* __restrict__ bk, const float* __restrict__ bv,
    u16* __restrict__ Qb, u16* __restrict__ Kt, u16* __restrict__ Vt)
{
  __shared__ __align__(16) u16 smem[2][2][128][72];   // [buf][A/B][row][64+8pad] = 73728 B

  const int tid = threadIdx.x;
  const int w = tid >> 6, lane = tid & 63;
  const int l31 = lane & 31, h = lane >> 5;
  const int m0 = blockIdx.x * 128;
  const int nblk = blockIdx.y;
  const int n0 = nblk * 128, mat = nblk >> 1, cb = (nblk & 1) * 128;
  const int mh = (w & 1) * 64, nh = (w >> 1) * 64;

  const int srow = tid & 127;
  const int isB = tid >> 7;
  const u16* sgbase = isB ? (Wc + (size_t)(n0 + srow)*512) : (xc + (size_t)(m0 + srow)*512);

  { // prologue: chunk 0 -> buf 0
    u16* d = &smem[0][isB][srow][0];
    #pragma unroll
    for (int jj=0; jj<8; ++jj) *(uint4*)(d + jj*8) = *(const uint4*)(sgbase + jj*8);
  }

  f32x16 acc[2][2];
  #pragma unroll
  for (int a=0;a<2;++a)
    #pragma unroll
    for (int c=0;c<2;++c)
      #pragma unroll
      for (int i=0;i<16;++i) acc[a][c][i] = 0.f;

  for (int kc8 = 0; kc8 < 8; ++kc8) {
    __syncthreads();
    const int p = kc8 & 1;
    uint4 nxt[8];
    if (kc8 < 7) {
      const u16* g = sgbase + (kc8+1)*64;
      #pragma unroll
      for (int jj=0; jj<8; ++jj) nxt[jj] = *(const uint4*)(g + jj*8);
    }
    #pragma unroll
    for (int kf = 0; kf < 4; ++kf) {
      const int ko = kf*16 + h*8;
      bf16x8 a0 = *(const bf16x8*)&smem[p][0][mh + l31][ko];
      bf16x8 a1 = *(const bf16x8*)&smem[p][0][mh + 32 + l31][ko];
      bf16x8 b0 = *(const bf16x8*)&smem[p][1][nh + l31][ko];
      bf16x8 b1 = *(const bf16x8*)&smem[p][1][nh + 32 + l31][ko];
      acc[0][0] = __builtin_amdgcn_mfma_f32_32x32x16_bf16(a0, b0, acc[0][0], 0,0,0);
      acc[0][1] = __builtin_amdgcn_mfma_f32_32x32x16_bf16(a0, b1, acc[0][1], 0,0,0);
      acc[1][0] = __builtin_amdgcn_mfma_f32_32x32x16_bf16(a1, b0, acc[1][0], 0,0,0);
      acc[1][1] = __builtin_amdgcn_mfma_f32_32x32x16_bf16(a1, b1, acc[1][1], 0,0,0);
    }
    if (kc8 < 7) {
      u16* d = &smem[p^1][isB][srow][0];
      #pragma unroll
      for (int jj=0; jj<8; ++jj) *(uint4*)(d + jj*8) = nxt[jj];
    }
  }

  const float* bias = mat==0 ? bq : (mat==1 ? bk : bv);
  const float bsc = (mat==0) ? 0.09016844005556021f : 1.0f;   // W pre-scaled; bias scaled here
  float bb_[2];
  #pragma unroll
  for (int ntl=0; ntl<2; ++ntl) bb_[ntl] = bias[cb + nh + ntl*32 + l31] * bsc;

  if (mat <= 1) {
    #pragma unroll
    for (int mt=0; mt<2; ++mt)
      #pragma unroll
      for (int ntl=0; ntl<2; ++ntl)
        #pragma unroll
        for (int r=0; r<16; ++r) {
          int gm = m0 + mh + mt*32 + (r&3) + 8*(r>>2) + 4*h;
          int col = cb + nh + ntl*32 + l31;
          u16 val = f2bf(acc[mt][ntl][r] + bb_[ntl]);
          if (mat == 0) {
            Qb[(size_t)gm*QSTR + col] = val;
          } else {
            int bb2 = gm >> 12, s = gm & (S-1);
            Kt[(size_t)(bb2*128 + (s>>5))*KT_TILE + (s&31)*280 + col] = val;
          }
        }
  } else {
    // V: transpose via LDS, store to Vt tiled [b][t32][e][40]
    u16* T = (u16*)smem;     // [128 e][136]
    #pragma unroll
    for (int mt=0; mt<2; ++mt)
      #pragma unroll
      for (int ntl=0; ntl<2; ++ntl)
        #pragma unroll
        for (int r=0; r<16; ++r) {
          int e_loc = nh + ntl*32 + l31;
          int m_loc = mh + mt*32 + (r&3) + 8*(r>>2) + 4*h;
          T[(size_t)e_loc*136 + m_loc] = f2bf(acc[mt][ntl][r] + bb_[ntl]);
        }
    __syncthreads();
    int e_loc = tid >> 1, shalf = (tid & 1)*64;
    int e = cb + e_loc;
    #pragma unroll
    for (int g2 = 0; g2 < 2; ++g2) {
      int gm = m0 + shalf + g2*32;
      int bb2 = gm >> 12, s = gm & (S-1);
      u16* dst = Vt + (size_t)(bb2*128 + (s>>5))*VT_TILE + (size_t)e*40;
      const u16* src = T + (size_t)e_loc*136 + shalf + g2*32;
      #pragma unroll
      for (int k2=0;k2<4;++k2) *(uint4*)(dst + k2*8) = *(const uint4*)(src + k2*8);
    }
  }
}

// ---------------- attention: BK=32, async dbuf (K AND V via global_load_lds), deferred ------
// softmax+PV pipeline with SPLIT-HALF softmax: pf0 computed first, stream A (QK 0..7 +
// all PV*ks0) consumes only pf0; pf1's VALU sits between the streams so the scheduler can
// hide it under the LDS-paced MFMA phase (combined softmax forced full completion before
// the 2nd MFMA -> ~1000 cy/SIMD of exposed VALU per iteration).
__global__ __launch_bounds__(256, 2) void msp_attn(
    const u16* __restrict__ Qb, const u16* __restrict__ Kt,
    const u16* __restrict__ Vt, float* __restrict__ out,
    float* __restrict__ P1, float* __restrict__ P23,
    float* __restrict__ Lacc)
{
  __shared__ __align__(16) unsigned char smem[77824];  // K dbuf 2x18432 | V dbuf 2x20480

  const int tid = threadIdx.x;
  const int w = tid >> 6, lane = tid & 63;
  const int l31 = lane & 31, h = lane >> 5;

  // XCD-swizzled decode over 512 blocks: 32 qt-blocks sharing (b,tq) land on one XCD
  const int xg = blockIdx.x;
  const int xcd = xg & 7, j = xg >> 3;
  const int c = xcd*2 + (j & 1);
  const int qt = j >> 1;
  const int b = c >> 2, tq = c & 3;
  const int q0 = qt * 128;
  const int qw = q0 + w*32;

  // Q fragments (B-operand): lane holds Q[qw+l31][16*s2 + 8h + j]
  bf16x8 qf[17];
  {
    const u16* qp = Qb + ((size_t)b*S + qw + l31)*QSTR + h*8;
    #pragma unroll
    for (int s2=0; s2<17; ++s2) qf[s2] = *(const bf16x8*)(qp + s2*16);
  }

  const int tIdx0 = b*128 + tq*32;

  f32x16 oacc[8];
  #pragma unroll
  for (int e=0;e<8;++e)
    #pragma unroll
    for (int i=0;i<16;++i) oacc[e][i] = 0.f;
  float l_acc = 0.f;

  { // prologue: K[0] -> k0
    const u16* kg = Kt + (size_t)tIdx0*KT_TILE;
    u16* kl = (u16*)smem;
    #pragma unroll
    for (int i = w; i < 18; i += 4) gl_lds16(kg + i*512 + lane*8, kl + i*512);
  }

  f32x16 sc_prev;

  { // peeled it = 0: stage K[1]->k1 + V[0]->v0; QK[0] from k0 (no softmax/PV yet)
    __syncthreads();
    const u16* kg = Kt + (size_t)(tIdx0 + 1)*KT_TILE;
    u16* kl = (u16*)(smem + 18432);
    #pragma unroll
    for (int i = w; i < 18; i += 4) gl_lds16(kg + i*512 + lane*8, kl + i*512);
    const u16* vg = Vt + (size_t)tIdx0*VT_TILE;
    u16* vl = (u16*)(smem + 36864);
    #pragma unroll
    for (int i = w; i < 20; i += 4) gl_lds16(vg + i*512 + lane*8, vl + i*512);

    const u16* Kp = (const u16*)smem + (size_t)l31*280 + h*8;
    f32x16 sa;
    #pragma unroll
    for (int i=0;i<16;++i) sa[i] = 0.f;
    __builtin_amdgcn_s_setprio(1);
    #pragma unroll
    for (int s2 = 0; s2 < 17; ++s2) {
      bf16x8 kf = *(const bf16x8*)(Kp + s2*16);
      sa = __builtin_amdgcn_mfma_f32_32x32x16_bf16(kf, qf[s2], sa, 0,0,0);
    }
    __builtin_amdgcn_s_setprio(0);
    sc_prev = sa;
  }

  for (int it = 1; it < 32; ++it) {
    const int p = it & 1;
    __syncthreads();            // drains K[it] (-> k[p]) and V[it-1] (-> v[p^1])

    if (it < 31) {              // stage K[it+1] -> k[p^1]
      const u16* kg = Kt + (size_t)(tIdx0 + it + 1)*KT_TILE;
      u16* kl = (u16*)(smem + (p^1)*18432);
      #pragma unroll
      for (int i = w; i < 18; i += 4) gl_lds16(kg + i*512 + lane*8, kl + i*512);
    }
    {                           // stage V[it] -> v[p]
      const u16* vg = Vt + (size_t)(tIdx0 + it)*VT_TILE;
      u16* vl = (u16*)(smem + 36864 + p*20480);
      #pragma unroll
      for (int i = w; i < 20; i += 4) gl_lds16(vg + i*512 + lane*8, vl + i*512);
    }

    const u16* Kp = (const u16*)(smem + p*18432) + (size_t)l31*280 + h*8;
    const u16* Vp = (const u16*)(smem + 36864 + (p^1)*20480) + (size_t)l31*40 + h*8;
    f32x16 sa;
    #pragma unroll
    for (int i=0;i<16;++i) sa[i] = 0.f;

    // half 0 of softmax[it-1] -> pf0 (stream A consumes only this)
    bf16x8 pf0 = softmax_half(sc_prev, 0, h, l_acc);

    __builtin_amdgcn_s_setprio(1);
    #pragma unroll
    for (int s2 = 0; s2 < 8; ++s2) {       // stream A: QK 0..7 + PV ks0 (pf0)
      bf16x8 kf = *(const bf16x8*)(Kp + s2*16);
      sa = __builtin_amdgcn_mfma_f32_32x32x16_bf16(kf, qf[s2], sa, 0,0,0);
      const u16* vb = Vp + s2*(32*40);
      oacc[s2] = __builtin_amdgcn_mfma_f32_32x32x16_bf16(*(const bf16x8*)vb, pf0, oacc[s2], 0,0,0);
    }
    __builtin_amdgcn_s_setprio(0);

    // half 1 of softmax[it-1] -> pf1 (VALU overlaps the MFMA streams)
    bf16x8 pf1 = softmax_half(sc_prev, 1, h, l_acc);

    __builtin_amdgcn_s_setprio(1);
    #pragma unroll
    for (int s2 = 8; s2 < 16; ++s2) {      // stream B: QK 8..15 + PV ks1 (pf1)
      bf16x8 kf = *(const bf16x8*)(Kp + s2*16);
      sa = __builtin_amdgcn_mfma_f32_32x32x16_bf16(kf, qf[s2], sa, 0,0,0);
      const u16* vb = Vp + (s2-8)*(32*40) + 16;
      oacc[s2-8] = __builtin_amdgcn_mfma_f32_32x32x16_bf16(*(const bf16x8*)vb, pf1, oacc[s2-8], 0,0,0);
    }
    {
      bf16x8 kf = *(const bf16x8*)(Kp + 16*16);
      sa = __builtin_amdgcn_mfma_f32_32x32x16_bf16(kf, qf[16], sa, 0,0,0);
    }
    __builtin_amdgcn_s_setprio(0);
    sc_prev = sa;
  }

  // tail: softmax[31], l-reduce, then PV[31] from v[1]
  bf16x8 pf0 = softmax_half(sc_prev, 0, h, l_acc);
  bf16x8 pf1 = softmax_half(sc_prev, 1, h, l_acc);

  float l_tot = l_acc + __shfl_xor(l_acc, 32, 64);
  if (h == 0) unsafeAtomicAdd(&Lacc[(size_t)b*S + qw + l31], l_tot);

  __syncthreads();              // drain V[31] (staged during it=31 into v[1])
  {
    const u16* Vp = (const u16*)(smem + 36864 + 20480) + (size_t)l31*40 + h*8;
    __builtin_amdgcn_s_setprio(1);
    #pragma unroll
    for (int et = 0; et < 8; ++et) {
      const u16* vb = Vp + et*32*40;
      oacc[et] = __builtin_amdgcn_mfma_f32_32x32x16_bf16(*(const bf16x8*)(vb),      pf0, oacc[et], 0,0,0);
      oacc[et] = __builtin_amdgcn_mfma_f32_32x32x16_bf16(*(const bf16x8*)(vb + 16), pf1, oacc[et], 0,0,0);
    }
    __builtin_amdgcn_s_setprio(0);
  }

  // transpose O^T -> O via LDS (2 double-width rounds), STREAMING float4 stores:
  // unique writer per (tq, b, q-row) -> no atomics, no RMW traffic
  float* dst = (tq == 0) ? (out + (size_t)b*S*D)
             : (tq == 1) ? (P1 + (size_t)b*S*D)
                         : (P23 + ((size_t)(tq-2)*4 + b)*S*D);
  float* OflA = (float*)smem;            // [32 q][260]
  float* OflB = (float*)smem + 8320;     // second buffer
  for (int rr = 0; rr < 2; ++rr) {
    __syncthreads();
    if ((w >> 1) == rr) {
      float* Of = (w & 1) ? OflB : OflA;
      #pragma unroll
      for (int et=0; et<8; ++et)
        #pragma unroll
        for (int g=0; g<4; ++g) {
          float4 v4 = { oacc[et][4*g+0], oacc[et][4*g+1], oacc[et][4*g+2], oacc[et][4*g+3] };
          *(float4*)&Of[(size_t)l31*260 + et*32 + 8*g + 4*h] = v4;
        }
    }
    __syncthreads();
    #pragma unroll
    for (int hf = 0; hf < 2; ++hf) {
      const float* Of = hf ? OflB : OflA;
      float* obase = dst + (size_t)(q0 + (rr*2 + hf)*32)*D;
      #pragma unroll
      for (int q2 = 0; q2 < 8; ++q2) {
        int q = q2*4 + (tid>>6);
        int e4 = (tid & 63)*4;
        *(float4*)(obase + (size_t)q*D + e4) = *(const float4*)&Of[(size_t)q*260 + e4];
      }
    }
  }
}

// ---------------- fused 4-way partial sum + normalize ----------------
__global__ __launch_bounds__(256) void msp_norm(
    float* __restrict__ out, const float* __restrict__ P1,
    const float* __restrict__ P23, const float* __restrict__ L)
{
  constexpr size_t PSZ = (size_t)4*S*D;   // floats per partial set (4 batches)
  int idx = blockIdx.x*256 + threadIdx.x;
  int row = idx >> 6, e0 = (idx & 63)*4;
  size_t off = (size_t)row*256 + e0;
  float inv = 1.0f / L[row];
  float4 v  = *(const float4*)(out + off);
  float4 a  = *(const float4*)(P1  + off);
  float4 b2 = *(const float4*)(P23 + off);
  float4 c2 = *(const float4*)(P23 + PSZ + off);
  v.x = (v.x + a.x + b2.x + c2.x) * inv;
  v.y = (v.y + a.y + b2.y + c2.y) * inv;
  v.z = (v.z + a.z + b2.z + c2.z) * inv;
  v.w = (v.w + a.w + b2.w + c2.w) * inv;
  *(float4*)(out + off) = v;
}

extern "C" void kernel_launch(void* const* d_in, const int* in_sizes, int n_in,
                              void* d_out, int out_size, void* d_ws, size_t ws_size,
                              hipStream_t stream) {
  const float* x    = (const float*)d_in[0];
  const float* Wq   = (const float*)d_in[1];
  const float* bq   = (const float*)d_in[2];
  const float* Wk   = (const float*)d_in[3];
  const float* bk   = (const float*)d_in[4];
  const float* Wv   = (const float*)d_in[5];
  const float* bv   = (const float*)d_in[6];
  const float* beta = (const float*)d_in[7];
  float* out = (float*)d_out;

  char* w = (char*)d_ws;
  u16* xc = (u16*)w;
  float* P1 = (float*)w;                            // overlays xc (dead after proj)
  w += (size_t)16384*512*2;                         // 16.8 MB
  u16* Wc = (u16*)w;  w += (size_t)768*512*2;       // 0.79 MB
  u16* Qb = (u16*)w;  w += (size_t)16384*QSTR*2;    // 8.9 MB
  u16* Kt = (u16*)w;  w += (size_t)512*KT_TILE*2;   // 9.2 MB (Vt must follow: junk-tail reads)
  u16* Vt = (u16*)w;  w += (size_t)512*VT_TILE*2;   // 10.5 MB
  float* Lacc = (float*)w; w += (size_t)16384*4;    // 64 KB
  float* P23 = (float*)w;                           // 2 x 16.8 MB

  msp_prep<<<2209, 256, 0, stream>>>(x, Wq, Wk, Wv, beta, xc, Wc, Qb, Kt, Lacc);
  msp_proj<<<dim3(128, 6), 256, 0, stream>>>(xc, Wc, bq, bk, bv, Qb, Kt, Vt);
  msp_attn<<<512, 256, 0, stream>>>(Qb, Kt, Vt, out, P1, P23, Lacc);
  msp_norm<<<4096, 256, 0, stream>>>(out, P1, P23, Lacc);
}

// Round 9
// 203.479 us; speedup vs baseline: 1.1507x; 1.1507x over previous
//
#include <hip/hip_runtime.h>
#include <math.h>
#include <stdint.h>

#define DEV static __device__ __forceinline__
typedef unsigned short u16;

constexpr int D = 256;
constexpr int S = 4096;
constexpr int QSTR = 272;            // Qb row: 256 data + 12 bias-ext + 4 zero
constexpr int KT_TILE = 8960;        // u16: 32 rows x 280
constexpr int VT_TILE = 10240;       // u16: 256 e-rows x 40 (padded for LDS bank spread)

typedef short bf16x8 __attribute__((ext_vector_type(8)));
typedef float f32x16 __attribute__((ext_vector_type(16)));

// RNE f32->bf16 via native convert (v_cvt_pk_bf16_f32)
DEV u16 f2bf(float f){ __bf16 b = (__bf16)f; return __builtin_bit_cast(u16, b); }
DEV float bf2f(u16 h){ return __uint_as_float(((unsigned)h)<<16); }
DEV int packbf(float lo, float hi){ return (int)((((unsigned)f2bf(hi)) << 16) | (unsigned)f2bf(lo)); }
DEV float bfsum2(int d){
  return __uint_as_float(((unsigned)d)<<16) + __uint_as_float(((unsigned)d) & 0xffff0000u);
}
DEV float ex2(float x){ return __builtin_amdgcn_exp2f(x); }   // v_exp_f32 (2^x native)
DEV void gl_lds16(const u16* g, u16* l) {
  __builtin_amdgcn_global_load_lds(
      (const __attribute__((address_space(1))) unsigned int*)g,
      (__attribute__((address_space(3))) unsigned int*)l, 16, 0, 0);
}

// softmax of one tile's scores (exp2 domain; log2e pre-folded into Q/bias)
// -> P^T B-fragments + running l. Called at the END of each iteration (pre-barrier):
// overlaps the other waves' MFMA phase + the DMA drain, and carrying pf (8 regs)
// across the barrier is cheaper than carrying sc (16 regs). [R8 lesson: regalloc
// sits at the 256/wave cliff -- changes must be register-neutral or negative.]
DEV void softmax_pf(const f32x16& s, int h, float& l_acc, bf16x8* pf) {
  #pragma unroll
  for (int s2 = 0; s2 < 2; ++s2) {
    float e0 = ex2(s[8*s2+0]), e1 = ex2(s[8*s2+1]);
    float e2 = ex2(s[8*s2+2]), e3 = ex2(s[8*s2+3]);
    float e4 = ex2(s[8*s2+4]), e5 = ex2(s[8*s2+5]);
    float e6 = ex2(s[8*s2+6]), e7 = ex2(s[8*s2+7]);
    int P0d0 = packbf(e0, e1), P0d1 = packbf(e2, e3);
    int P1d0 = packbf(e4, e5), P1d1 = packbf(e6, e7);
    // l sums the bf16-ROUNDED p so normalization cancels rounding bias
    l_acc += bfsum2(P0d0) + bfsum2(P0d1) + bfsum2(P1d0) + bfsum2(P1d1);
    int s0 = h ? P0d0 : P1d0;
    int s1 = h ? P0d1 : P1d1;
    int r0 = __shfl_xor(s0, 32, 64);
    int r1 = __shfl_xor(s1, 32, 64);
    union { int d[4]; bf16x8 v; } u;
    u.d[0] = h ? r0 : P0d0;
    u.d[1] = h ? r1 : P0d1;
    u.d[2] = h ? P1d0 : r0;
    u.d[3] = h ? P1d1 : r1;
    pf[s2] = u.v;
  }
}

// ---------------- prep: hi/lo split (interleaved layouts), bias-ext cols, zero Lacc -----
__global__ __launch_bounds__(256) void msp_prep(
    const float* __restrict__ x, const float* __restrict__ Wq,
    const float* __restrict__ Wk, const float* __restrict__ Wv,
    const float* __restrict__ beta,
    u16* __restrict__ xc, u16* __restrict__ Wc,
    u16* __restrict__ Qb, u16* __restrict__ Kt,
    float* __restrict__ Lacc)
{
  const int blk = blockIdx.x, tid = threadIdx.x;
  if (blk < 2048) {                       // xc[row][0..255]=hi, [256..511]=lo
    int row = blk*8 + (tid>>5);
    int col = (tid&31)*8;
    const float* p = x + (size_t)row*256 + col;
    union { u16 s[8]; uint4 v; } hh, ll;
    #pragma unroll
    for (int i=0;i<8;++i){ float v = p[i]; u16 h2 = f2bf(v); hh.s[i]=h2; ll.s[i]=f2bf(v - bf2f(h2)); }
    *(uint4*)(xc + (size_t)row*512 + col)       = hh.v;
    *(uint4*)(xc + (size_t)row*512 + 256 + col) = ll.v;
  } else if (blk < 2144) {                // Wc rows: [0,256)=Wq*log2e/16, [256,512)=Wk, [512,768)=Wv
    int q = blk - 2048;                   // 96 blocks
    int mat = q >> 5;
    int idx = (q & 31)*2048 + tid*8;      // 0..65535
    int o = idx >> 8, cc = idx & 255;
    const float* W = mat==0 ? Wq : (mat==1 ? Wk : Wv);
    float sc = (mat==0) ? 0.09016844005556021f : 1.0f;   // (1/16)*log2(e) folded on Q side
    const float* p = W + (size_t)o*256 + cc;
    union { u16 s[8]; uint4 v; } hh, ll;
    #pragma unroll
    for (int i=0;i<8;++i){ float v = p[i]*sc; u16 h2 = f2bf(v); hh.s[i]=h2; ll.s[i]=f2bf(v - bf2f(h2)); }
    *(uint4*)(Wc + (size_t)(mat*256 + o)*512 + cc)       = hh.v;
    *(uint4*)(Wc + (size_t)(mat*256 + o)*512 + 256 + cc) = ll.v;
  } else if (blk < 2208) {                // bias-ext cols (64 blocks)
    int row = (blk - 2144)*256 + tid;     // b*4096 + s
    int s = row & (S-1);
    int bb = row >> 12;
    constexpr float L2E = 1.4426950408889634f;
    float b0 = beta[0]*L2E, b1 = beta[1]*L2E;   // exp2-domain: log2e on Q side
    int i24 = s % 24, i720 = s % 720;
    float t0 = (float)i24  * 0.26179938779914944f;    // 2pi/24
    float t1 = (float)i720 * 0.008726646259971648f;   // 2pi/720
    float c0 = cosf(t0), s0 = sinf(t0), c1 = cosf(t1), s1 = sinf(t1);
    float qv[4] = {b0*c0, b0*s0, b1*c1, b1*s1};   // beta folded on Q side
    float kv[4] = {c0, s0, c1, s1};
    u16* qp = Qb + (size_t)row*QSTR + 256;
    u16* kp = Kt + (size_t)(bb*128 + (s>>5))*KT_TILE + (s&31)*280 + 256;
    #pragma unroll
    for (int n=0;n<4;++n){
      u16 uh = f2bf(qv[n]); u16 ul = f2bf(qv[n]-bf2f(uh));
      u16 vh = f2bf(kv[n]); u16 vl = f2bf(kv[n]-bf2f(vh));
      // dot over triplet = uh*vh + uh*vl + ul*vh ~= u*v (drops ul*vl <= 2^-18)
      qp[n*3+0]=uh; qp[n*3+1]=uh; qp[n*3+2]=ul;
      kp[n*3+0]=vh; kp[n*3+1]=vl; kp[n*3+2]=vh;
    }
    #pragma unroll
    for (int c=12;c<16;++c){ qp[c]=0; kp[c]=0; }
  } else {                                // zero Lacc (16384 f32)
    float4* p = (float4*)Lacc;
    float4 z = {0.f,0.f,0.f,0.f};
    #pragma unroll
    for (int c=0;c<16;++c) p[tid + c*256] = z;
  }
}

// ---------------- fused projection GEMM: C[16384x768] = xc . Wc^T, route Q/K/V ----------------
__global__ __launch_bounds__(256, 2) void msp_proj(
    const u16* __restrict__ xc, const u16* __restrict__ Wc,
    const float* __restrict__ bq, const float* __restrict__ bk, const float* __restrict__ bv,
    u16* __restrict__ Qb, u16* __restrict__ Kt, u16* __restrict__ Vt)
{
  __shared__ __align__(16) u16 smem[2][2][128][72];   // [buf][A/B][row][64+8pad] = 73728 B

  const int tid = threadIdx.x;
  const int w = tid >> 6, lane = tid & 63;
  const int l31 = lane & 31, h = lane >> 5;
  const int m0 = blockIdx.x * 128;
  const int nblk = blockIdx.y;
  const int n0 = nblk * 128, mat = nblk >> 1, cb = (nblk & 1) * 128;
  const int mh = (w & 1) * 64, nh = (w >> 1) * 64;

  const int srow = tid & 127;
  const int isB = tid >> 7;
  const u16* sgbase = isB ? (Wc + (size_t)(n0 + srow)*512) : (xc + (size_t)(m0 + srow)*512);

  { // prologue: chunk 0 -> buf 0
    u16* d = &smem[0][isB][srow][0];
    #pragma unroll
    for (int jj=0; jj<8; ++jj) *(uint4*)(d + jj*8) = *(const uint4*)(sgbase + jj*8);
  }

  f32x16 acc[2][2];
  #pragma unroll
  for (int a=0;a<2;++a)
    #pragma unroll
    for (int c=0;c<2;++c)
      #pragma unroll
      for (int i=0;i<16;++i) acc[a][c][i] = 0.f;

  for (int kc8 = 0; kc8 < 8; ++kc8) {
    __syncthreads();
    const int p = kc8 & 1;
    uint4 nxt[8];
    if (kc8 < 7) {
      const u16* g = sgbase + (kc8+1)*64;
      #pragma unroll
      for (int jj=0; jj<8; ++jj) nxt[jj] = *(const uint4*)(g + jj*8);
    }
    #pragma unroll
    for (int kf = 0; kf < 4; ++kf) {
      const int ko = kf*16 + h*8;
      bf16x8 a0 = *(const bf16x8*)&smem[p][0][mh + l31][ko];
      bf16x8 a1 = *(const bf16x8*)&smem[p][0][mh + 32 + l31][ko];
      bf16x8 b0 = *(const bf16x8*)&smem[p][1][nh + l31][ko];
      bf16x8 b1 = *(const bf16x8*)&smem[p][1][nh + 32 + l31][ko];
      acc[0][0] = __builtin_amdgcn_mfma_f32_32x32x16_bf16(a0, b0, acc[0][0], 0,0,0);
      acc[0][1] = __builtin_amdgcn_mfma_f32_32x32x16_bf16(a0, b1, acc[0][1], 0,0,0);
      acc[1][0] = __builtin_amdgcn_mfma_f32_32x32x16_bf16(a1, b0, acc[1][0], 0,0,0);
      acc[1][1] = __builtin_amdgcn_mfma_f32_32x32x16_bf16(a1, b1, acc[1][1], 0,0,0);
    }
    if (kc8 < 7) {
      u16* d = &smem[p^1][isB][srow][0];
      #pragma unroll
      for (int jj=0; jj<8; ++jj) *(uint4*)(d + jj*8) = nxt[jj];
    }
  }

  const float* bias = mat==0 ? bq : (mat==1 ? bk : bv);
  const float bsc = (mat==0) ? 0.09016844005556021f : 1.0f;   // W pre-scaled; bias scaled here
  float bb_[2];
  #pragma unroll
  for (int ntl=0; ntl<2; ++ntl) bb_[ntl] = bias[cb + nh + ntl*32 + l31] * bsc;

  if (mat <= 1) {
    #pragma unroll
    for (int mt=0; mt<2; ++mt)
      #pragma unroll
      for (int ntl=0; ntl<2; ++ntl)
        #pragma unroll
        for (int r=0; r<16; ++r) {
          int gm = m0 + mh + mt*32 + (r&3) + 8*(r>>2) + 4*h;
          int col = cb + nh + ntl*32 + l31;
          u16 val = f2bf(acc[mt][ntl][r] + bb_[ntl]);
          if (mat == 0) {
            Qb[(size_t)gm*QSTR + col] = val;
          } else {
            int bb2 = gm >> 12, s = gm & (S-1);
            Kt[(size_t)(bb2*128 + (s>>5))*KT_TILE + (s&31)*280 + col] = val;
          }
        }
  } else {
    // V: transpose via LDS, store to Vt tiled [b][t32][e][40]
    u16* T = (u16*)smem;     // [128 e][136]
    #pragma unroll
    for (int mt=0; mt<2; ++mt)
      #pragma unroll
      for (int ntl=0; ntl<2; ++ntl)
        #pragma unroll
        for (int r=0; r<16; ++r) {
          int e_loc = nh + ntl*32 + l31;
          int m_loc = mh + mt*32 + (r&3) + 8*(r>>2) + 4*h;
          T[(size_t)e_loc*136 + m_loc] = f2bf(acc[mt][ntl][r] + bb_[ntl]);
        }
    __syncthreads();
    int e_loc = tid >> 1, shalf = (tid & 1)*64;
    int e = cb + e_loc;
    #pragma unroll
    for (int g2 = 0; g2 < 2; ++g2) {
      int gm = m0 + shalf + g2*32;
      int bb2 = gm >> 12, s = gm & (S-1);
      u16* dst = Vt + (size_t)(bb2*128 + (s>>5))*VT_TILE + (size_t)e*40;
      const u16* src = T + (size_t)e_loc*136 + shalf + g2*32;
      #pragma unroll
      for (int k2=0;k2<4;++k2) *(uint4*)(dst + k2*8) = *(const uint4*)(src + k2*8);
    }
  }
}

// ---------------- attention: BK=32, async dbuf (K AND V via global_load_lds) ----------------
// Deferred softmax+PV pipeline, softmax PRE-BARRIER: pf[it] is computed at the END of
// iteration it (right after the QK chain), so it overlaps other waves' MFMA phase and the
// DMA drain; post-barrier code goes straight to MFMA. Carries pf (8 regs) instead of
// sc (16 regs) across the barrier -> -8 register pressure (R5/R8 died at the 256 cliff).
__global__ __launch_bounds__(256, 2) void msp_attn(
    const u16* __restrict__ Qb, const u16* __restrict__ Kt,
    const u16* __restrict__ Vt, float* __restrict__ out,
    float* __restrict__ P1, float* __restrict__ P23,
    float* __restrict__ Lacc)
{
  __shared__ __align__(16) unsigned char smem[77824];  // K dbuf 2x18432 | V dbuf 2x20480

  const int tid = threadIdx.x;
  const int w = tid >> 6, lane = tid & 63;
  const int l31 = lane & 31, h = lane >> 5;

  // XCD-swizzled decode over 512 blocks: 32 qt-blocks sharing (b,tq) land on one XCD
  const int xg = blockIdx.x;
  const int xcd = xg & 7, j = xg >> 3;
  const int c = xcd*2 + (j & 1);
  const int qt = j >> 1;
  const int b = c >> 2, tq = c & 3;
  const int q0 = qt * 128;
  const int qw = q0 + w*32;

  // Q fragments (B-operand): lane holds Q[qw+l31][16*s2 + 8h + j]
  bf16x8 qf[17];
  {
    const u16* qp = Qb + ((size_t)b*S + qw + l31)*QSTR + h*8;
    #pragma unroll
    for (int s2=0; s2<17; ++s2) qf[s2] = *(const bf16x8*)(qp + s2*16);
  }

  const int tIdx0 = b*128 + tq*32;

  f32x16 oacc[8];
  #pragma unroll
  for (int e=0;e<8;++e)
    #pragma unroll
    for (int i=0;i<16;++i) oacc[e][i] = 0.f;
  float l_acc = 0.f;

  { // prologue: K[0] -> k0
    const u16* kg = Kt + (size_t)tIdx0*KT_TILE;
    u16* kl = (u16*)smem;
    #pragma unroll
    for (int i = w; i < 18; i += 4) gl_lds16(kg + i*512 + lane*8, kl + i*512);
  }

  bf16x8 pf[2];   // carried P^T fragments (softmax computed pre-barrier)

  { // peeled it = 0: stage K[1]->k1 + V[0]->v0; QK[0] from k0; softmax[0] pre-barrier
    __syncthreads();
    const u16* kg = Kt + (size_t)(tIdx0 + 1)*KT_TILE;
    u16* kl = (u16*)(smem + 18432);
    #pragma unroll
    for (int i = w; i < 18; i += 4) gl_lds16(kg + i*512 + lane*8, kl + i*512);
    const u16* vg = Vt + (size_t)tIdx0*VT_TILE;
    u16* vl = (u16*)(smem + 36864);
    #pragma unroll
    for (int i = w; i < 20; i += 4) gl_lds16(vg + i*512 + lane*8, vl + i*512);

    const u16* Kp = (const u16*)smem + (size_t)l31*280 + h*8;
    f32x16 sa;
    #pragma unroll
    for (int i=0;i<16;++i) sa[i] = 0.f;
    __builtin_amdgcn_s_setprio(1);
    #pragma unroll
    for (int s2 = 0; s2 < 17; ++s2) {
      bf16x8 kf = *(const bf16x8*)(Kp + s2*16);
      sa = __builtin_amdgcn_mfma_f32_32x32x16_bf16(kf, qf[s2], sa, 0,0,0);
    }
    __builtin_amdgcn_s_setprio(0);
    softmax_pf(sa, h, l_acc, pf);      // pre-barrier: overlaps DMA drain
  }

  for (int it = 1; it < 32; ++it) {
    const int p = it & 1;
    __syncthreads();            // drains K[it] (-> k[p]) and V[it-1] (-> v[p^1])

    if (it < 31) {              // stage K[it+1] -> k[p^1]
      const u16* kg = Kt + (size_t)(tIdx0 + it + 1)*KT_TILE;
      u16* kl = (u16*)(smem + (p^1)*18432);
      #pragma unroll
      for (int i = w; i < 18; i += 4) gl_lds16(kg + i*512 + lane*8, kl + i*512);
    }
    {                           // stage V[it] -> v[p]
      const u16* vg = Vt + (size_t)(tIdx0 + it)*VT_TILE;
      u16* vl = (u16*)(smem + 36864 + p*20480);
      #pragma unroll
      for (int i = w; i < 20; i += 4) gl_lds16(vg + i*512 + lane*8, vl + i*512);
    }

    // QK[it] (chain sa) interleaved with PV[it-1] (carried pf, independent accumulators)
    const u16* Kp = (const u16*)(smem + p*18432) + (size_t)l31*280 + h*8;
    const u16* Vp = (const u16*)(smem + 36864 + (p^1)*20480) + (size_t)l31*40 + h*8;
    f32x16 sa;
    #pragma unroll
    for (int i=0;i<16;++i) sa[i] = 0.f;
    __builtin_amdgcn_s_setprio(1);
    #pragma unroll
    for (int s2 = 0; s2 < 17; ++s2) {
      bf16x8 kf = *(const bf16x8*)(Kp + s2*16);
      sa = __builtin_amdgcn_mfma_f32_32x32x16_bf16(kf, qf[s2], sa, 0,0,0);
      if (s2 < 16) {
        const u16* vb = Vp + (s2>>1)*(32*40) + (s2&1)*16;
        oacc[s2>>1] = __builtin_amdgcn_mfma_f32_32x32x16_bf16(*(const bf16x8*)vb, pf[s2&1], oacc[s2>>1], 0,0,0);
      }
    }
    __builtin_amdgcn_s_setprio(0);

    // softmax[it] pre-barrier -> new pf (old pf consumed by the PV MFMAs above)
    softmax_pf(sa, h, l_acc, pf);
  }

  // tail: l-reduce, then PV[31] from v[1] with the carried pf
  float l_tot = l_acc + __shfl_xor(l_acc, 32, 64);
  if (h == 0) unsafeAtomicAdd(&Lacc[(size_t)b*S + qw + l31], l_tot);

  __syncthreads();              // drain V[31] (staged during it=31 into v[1])
  {
    const u16* Vp = (const u16*)(smem + 36864 + 20480) + (size_t)l31*40 + h*8;
    __builtin_amdgcn_s_setprio(1);
    #pragma unroll
    for (int et = 0; et < 8; ++et) {
      const u16* vb = Vp + et*32*40;
      oacc[et] = __builtin_amdgcn_mfma_f32_32x32x16_bf16(*(const bf16x8*)(vb),      pf[0], oacc[et], 0,0,0);
      oacc[et] = __builtin_amdgcn_mfma_f32_32x32x16_bf16(*(const bf16x8*)(vb + 16), pf[1], oacc[et], 0,0,0);
    }
    __builtin_amdgcn_s_setprio(0);
  }

  // transpose O^T -> O via LDS (2 double-width rounds), STREAMING float4 stores:
  // unique writer per (tq, b, q-row) -> no atomics, no RMW traffic
  float* dst = (tq == 0) ? (out + (size_t)b*S*D)
             : (tq == 1) ? (P1 + (size_t)b*S*D)
                         : (P23 + ((size_t)(tq-2)*4 + b)*S*D);
  float* OflA = (float*)smem;            // [32 q][260]
  float* OflB = (float*)smem + 8320;     // second buffer
  for (int rr = 0; rr < 2; ++rr) {
    __syncthreads();
    if ((w >> 1) == rr) {
      float* Of = (w & 1) ? OflB : OflA;
      #pragma unroll
      for (int et=0; et<8; ++et)
        #pragma unroll
        for (int g=0; g<4; ++g) {
          float4 v4 = { oacc[et][4*g+0], oacc[et][4*g+1], oacc[et][4*g+2], oacc[et][4*g+3] };
          *(float4*)&Of[(size_t)l31*260 + et*32 + 8*g + 4*h] = v4;
        }
    }
    __syncthreads();
    #pragma unroll
    for (int hf = 0; hf < 2; ++hf) {
      const float* Of = hf ? OflB : OflA;
      float* obase = dst + (size_t)(q0 + (rr*2 + hf)*32)*D;
      #pragma unroll
      for (int q2 = 0; q2 < 8; ++q2) {
        int q = q2*4 + (tid>>6);
        int e4 = (tid & 63)*4;
        *(float4*)(obase + (size_t)q*D + e4) = *(const float4*)&Of[(size_t)q*260 + e4];
      }
    }
  }
}

// ---------------- fused 4-way partial sum + normalize ----------------
__global__ __launch_bounds__(256) void msp_norm(
    float* __restrict__ out, const float* __restrict__ P1,
    const float* __restrict__ P23, const float* __restrict__ L)
{
  constexpr size_t PSZ = (size_t)4*S*D;   // floats per partial set (4 batches)
  int idx = blockIdx.x*256 + threadIdx.x;
  int row = idx >> 6, e0 = (idx & 63)*4;
  size_t off = (size_t)row*256 + e0;
  float inv = 1.0f / L[row];
  float4 v  = *(const float4*)(out + off);
  float4 a  = *(const float4*)(P1  + off);
  float4 b2 = *(const float4*)(P23 + off);
  float4 c2 = *(const float4*)(P23 + PSZ + off);
  v.x = (v.x + a.x + b2.x + c2.x) * inv;
  v.y = (v.y + a.y + b2.y + c2.y) * inv;
  v.z = (v.z + a.z + b2.z + c2.z) * inv;
  v.w = (v.w + a.w + b2.w + c2.w) * inv;
  *(float4*)(out + off) = v;
}

extern "C" void kernel_launch(void* const* d_in, const int* in_sizes, int n_in,
                              void* d_out, int out_size, void* d_ws, size_t ws_size,
                              hipStream_t stream) {
  const float* x    = (const float*)d_in[0];
  const float* Wq   = (const float*)d_in[1];
  const float* bq   = (const float*)d_in[2];
  const float* Wk   = (const float*)d_in[3];
  const float* bk   = (const float*)d_in[4];
  const float* Wv   = (const float*)d_in[5];
  const float* bv   = (const float*)d_in[6];
  const float* beta = (const float*)d_in[7];
  float* out = (float*)d_out;

  char* w = (char*)d_ws;
  u16* xc = (u16*)w;
  float* P1 = (float*)w;                            // overlays xc (dead after proj)
  w += (size_t)16384*512*2;                         // 16.8 MB
  u16* Wc = (u16*)w;  w += (size_t)768*512*2;       // 0.79 MB
  u16* Qb = (u16*)w;  w += (size_t)16384*QSTR*2;    // 8.9 MB
  u16* Kt = (u16*)w;  w += (size_t)512*KT_TILE*2;   // 9.2 MB (Vt must follow: junk-tail reads)
  u16* Vt = (u16*)w;  w += (size_t)512*VT_TILE*2;   // 10.5 MB
  float* Lacc = (float*)w; w += (size_t)16384*4;    // 64 KB
  float* P23 = (float*)w;                           // 2 x 16.8 MB

  msp_prep<<<2209, 256, 0, stream>>>(x, Wq, Wk, Wv, beta, xc, Wc, Qb, Kt, Lacc);
  msp_proj<<<dim3(128, 6), 256, 0, stream>>>(xc, Wc, bq, bk, bv, Qb, Kt, Vt);
  msp_attn<<<512, 256, 0, stream>>>(Qb, Kt, Vt, out, P1, P23, Lacc);
  msp_norm<<<4096, 256, 0, stream>>>(out, P1, P23, Lacc);
}

// Round 10
// 192.882 us; speedup vs baseline: 1.2140x; 1.0549x over previous
//
#include <hip/hip_runtime.h>
#include <math.h>
#include <stdint.h>

#define DEV static __device__ __forceinline__
typedef unsigned short u16;

constexpr int D = 256;
constexpr int S = 4096;
constexpr int QSTR = 272;            // Qb row: 256 data + 12 bias-ext + 4 zero
constexpr int KT_TILE = 8960;        // u16: 32 rows x 280
constexpr int VT_TILE = 10240;       // u16: 256 e-rows x 40 (padded for LDS bank spread)

typedef short bf16x8 __attribute__((ext_vector_type(8)));
typedef float f32x16 __attribute__((ext_vector_type(16)));

// RNE f32->bf16 via native convert (v_cvt_pk_bf16_f32)
DEV u16 f2bf(float f){ __bf16 b = (__bf16)f; return __builtin_bit_cast(u16, b); }
DEV float bf2f(u16 h){ return __uint_as_float(((unsigned)h)<<16); }
DEV int packbf(float lo, float hi){ return (int)((((unsigned)f2bf(hi)) << 16) | (unsigned)f2bf(lo)); }
DEV float bfsum2(int d){
  return __uint_as_float(((unsigned)d)<<16) + __uint_as_float(((unsigned)d) & 0xffff0000u);
}
DEV float ex2(float x){ return __builtin_amdgcn_exp2f(x); }   // v_exp_f32 (2^x native)
DEV void gl_lds16(const u16* g, u16* l) {
  __builtin_amdgcn_global_load_lds(
      (const __attribute__((address_space(1))) unsigned int*)g,
      (__attribute__((address_space(3))) unsigned int*)l, 16, 0, 0);
}

// xc/Wc chunk-major + XOR-swizzled 16B-slot addressing (rule #21: linear gl_lds dest,
// inverse-swizzled SOURCE written by prep, swizzled ds_read in proj).
// Chunk = [128 rows][64 u16] = 16KB contiguous; slot j = 16B granule (8 u16).
DEV size_t cm_addr(int rowblock, int chunk, int row_in, int j) {
  return ((size_t)rowblock*8 + chunk)*8192 + (size_t)(((row_in<<3) + j) ^ (row_in & 7))*8;
}
DEV const u16* swz(const u16* base, int row, int slot) {
  return base + ((((row<<3) + slot) ^ (row & 7)) << 3);
}

// softmax of one tile's scores (exp2 domain; log2e pre-folded into Q/bias)
// -> P^T B-fragments + running l. Called at the END of each iteration (pre-barrier):
// overlaps the other waves' MFMA phase + the DMA drain; carries pf (8 regs) not sc (16).
DEV void softmax_pf(const f32x16& s, int h, float& l_acc, bf16x8* pf) {
  #pragma unroll
  for (int s2 = 0; s2 < 2; ++s2) {
    float e0 = ex2(s[8*s2+0]), e1 = ex2(s[8*s2+1]);
    float e2 = ex2(s[8*s2+2]), e3 = ex2(s[8*s2+3]);
    float e4 = ex2(s[8*s2+4]), e5 = ex2(s[8*s2+5]);
    float e6 = ex2(s[8*s2+6]), e7 = ex2(s[8*s2+7]);
    int P0d0 = packbf(e0, e1), P0d1 = packbf(e2, e3);
    int P1d0 = packbf(e4, e5), P1d1 = packbf(e6, e7);
    // l sums the bf16-ROUNDED p so normalization cancels rounding bias
    l_acc += bfsum2(P0d0) + bfsum2(P0d1) + bfsum2(P1d0) + bfsum2(P1d1);
    int s0 = h ? P0d0 : P1d0;
    int s1 = h ? P0d1 : P1d1;
    int r0 = __shfl_xor(s0, 32, 64);
    int r1 = __shfl_xor(s1, 32, 64);
    union { int d[4]; bf16x8 v; } u;
    u.d[0] = h ? r0 : P0d0;
    u.d[1] = h ? r1 : P0d1;
    u.d[2] = h ? P1d0 : r0;
    u.d[3] = h ? P1d1 : r1;
    pf[s2] = u.v;
  }
}

// ---------------- prep: hi/lo split (chunk-major swizzled layouts), bias-ext, zero Lacc ----
__global__ __launch_bounds__(256) void msp_prep(
    const float* __restrict__ x, const float* __restrict__ Wq,
    const float* __restrict__ Wk, const float* __restrict__ Wv,
    const float* __restrict__ beta,
    u16* __restrict__ xc, u16* __restrict__ Wc,
    u16* __restrict__ Qb, u16* __restrict__ Kt,
    float* __restrict__ Lacc)
{
  const int blk = blockIdx.x, tid = threadIdx.x;
  if (blk < 2048) {                       // xc: hi in chunks 0..3, lo in chunks 4..7
    int row = blk*8 + (tid>>5);
    int col = (tid&31)*8;
    const float* p = x + (size_t)row*256 + col;
    union { u16 s[8]; uint4 v; } hh, ll;
    #pragma unroll
    for (int i=0;i<8;++i){ float v = p[i]; u16 h2 = f2bf(v); hh.s[i]=h2; ll.s[i]=f2bf(v - bf2f(h2)); }
    int rb = row >> 7, rin = row & 127;
    int ch = col >> 6, j = (col >> 3) & 7;
    *(uint4*)(xc + cm_addr(rb, ch,     rin, j)) = hh.v;
    *(uint4*)(xc + cm_addr(rb, ch + 4, rin, j)) = ll.v;
  } else if (blk < 2144) {                // Wc rows: [0,256)=Wq*log2e/16, [256,512)=Wk, [512,768)=Wv
    int q = blk - 2048;                   // 96 blocks
    int mat = q >> 5;
    int idx = (q & 31)*2048 + tid*8;      // 0..65535
    int o = idx >> 8, cc = idx & 255;
    const float* W = mat==0 ? Wq : (mat==1 ? Wk : Wv);
    float sc = (mat==0) ? 0.09016844005556021f : 1.0f;   // (1/16)*log2(e) folded on Q side
    const float* p = W + (size_t)o*256 + cc;
    union { u16 s[8]; uint4 v; } hh, ll;
    #pragma unroll
    for (int i=0;i<8;++i){ float v = p[i]*sc; u16 h2 = f2bf(v); hh.s[i]=h2; ll.s[i]=f2bf(v - bf2f(h2)); }
    int rowg = mat*256 + o;
    int rb = rowg >> 7, rin = rowg & 127;
    int ch = cc >> 6, j = (cc >> 3) & 7;
    *(uint4*)(Wc + cm_addr(rb, ch,     rin, j)) = hh.v;
    *(uint4*)(Wc + cm_addr(rb, ch + 4, rin, j)) = ll.v;
  } else if (blk < 2208) {                // bias-ext cols (64 blocks)
    int row = (blk - 2144)*256 + tid;     // b*4096 + s
    int s = row & (S-1);
    int bb = row >> 12;
    constexpr float L2E = 1.4426950408889634f;
    float b0 = beta[0]*L2E, b1 = beta[1]*L2E;   // exp2-domain: log2e on Q side
    int i24 = s % 24, i720 = s % 720;
    float t0 = (float)i24  * 0.26179938779914944f;    // 2pi/24
    float t1 = (float)i720 * 0.008726646259971648f;   // 2pi/720
    float c0 = cosf(t0), s0 = sinf(t0), c1 = cosf(t1), s1 = sinf(t1);
    float qv[4] = {b0*c0, b0*s0, b1*c1, b1*s1};   // beta folded on Q side
    float kv[4] = {c0, s0, c1, s1};
    u16* qp = Qb + (size_t)row*QSTR + 256;
    u16* kp = Kt + (size_t)(bb*128 + (s>>5))*KT_TILE + (s&31)*280 + 256;
    #pragma unroll
    for (int n=0;n<4;++n){
      u16 uh = f2bf(qv[n]); u16 ul = f2bf(qv[n]-bf2f(uh));
      u16 vh = f2bf(kv[n]); u16 vl = f2bf(kv[n]-bf2f(vh));
      // dot over triplet = uh*vh + uh*vl + ul*vh ~= u*v (drops ul*vl <= 2^-18)
      qp[n*3+0]=uh; qp[n*3+1]=uh; qp[n*3+2]=ul;
      kp[n*3+0]=vh; kp[n*3+1]=vl; kp[n*3+2]=vh;
    }
    #pragma unroll
    for (int c=12;c<16;++c){ qp[c]=0; kp[c]=0; }
  } else {                                // zero Lacc (16384 f32)
    float4* p = (float4*)Lacc;
    float4 z = {0.f,0.f,0.f,0.f};
    #pragma unroll
    for (int c=0;c<16;++c) p[tid + c*256] = z;
  }
}

// ---------------- fused projection GEMM: C[16384x768] = xc . Wc^T, route Q/K/V ----------------
// Staging now via global_load_lds (1024B coalesced DMA per wave-instr) from the chunk-major
// pre-swizzled xc/Wc; ds_reads apply the XOR -> conflict-free, no register round-trip.
__global__ __launch_bounds__(256, 2) void msp_proj(
    const u16* __restrict__ xc, const u16* __restrict__ Wc,
    const float* __restrict__ bq, const float* __restrict__ bk, const float* __restrict__ bv,
    u16* __restrict__ Qb, u16* __restrict__ Kt, u16* __restrict__ Vt)
{
  __shared__ __align__(16) u16 smem[2][2][128][64];   // [buf][A/B][row][64] = 65536 B, swizzled

  const int tid = threadIdx.x;
  const int w = tid >> 6, lane = tid & 63;
  const int l31 = lane & 31, h = lane >> 5;
  const int m0 = blockIdx.x * 128;
  const int nblk = blockIdx.y;
  const int mat = nblk >> 1, cb = (nblk & 1) * 128;
  const int mh = (w & 1) * 64, nh = (w >> 1) * 64;

  const u16* Ag = xc + (size_t)blockIdx.x*8*8192;   // + kc8*8192
  const u16* Bg = Wc + (size_t)nblk*8*8192;

  { // prologue: chunk 0 -> buf 0 (async DMA)
    #pragma unroll
    for (int i = w; i < 16; i += 4) gl_lds16(Ag + i*512 + lane*8, &smem[0][0][0][0] + i*512);
    #pragma unroll
    for (int i = w; i < 16; i += 4) gl_lds16(Bg + i*512 + lane*8, &smem[0][1][0][0] + i*512);
  }

  f32x16 acc[2][2];
  #pragma unroll
  for (int a=0;a<2;++a)
    #pragma unroll
    for (int c=0;c<2;++c)
      #pragma unroll
      for (int i=0;i<16;++i) acc[a][c][i] = 0.f;

  for (int kc8 = 0; kc8 < 8; ++kc8) {
    __syncthreads();            // drains chunk kc8 into buf p
    const int p = kc8 & 1;
    if (kc8 < 7) {              // stage chunk kc8+1 -> buf p^1
      const u16* a2 = Ag + (size_t)(kc8+1)*8192;
      const u16* b2 = Bg + (size_t)(kc8+1)*8192;
      #pragma unroll
      for (int i = w; i < 16; i += 4) gl_lds16(a2 + i*512 + lane*8, &smem[p^1][0][0][0] + i*512);
      #pragma unroll
      for (int i = w; i < 16; i += 4) gl_lds16(b2 + i*512 + lane*8, &smem[p^1][1][0][0] + i*512);
    }
    const u16* As = &smem[p][0][0][0];
    const u16* Bs = &smem[p][1][0][0];
    #pragma unroll
    for (int kf = 0; kf < 4; ++kf) {
      const int slot = kf*2 + h;
      bf16x8 a0 = *(const bf16x8*)swz(As, mh + l31, slot);
      bf16x8 a1 = *(const bf16x8*)swz(As, mh + 32 + l31, slot);
      bf16x8 b0 = *(const bf16x8*)swz(Bs, nh + l31, slot);
      bf16x8 b1 = *(const bf16x8*)swz(Bs, nh + 32 + l31, slot);
      acc[0][0] = __builtin_amdgcn_mfma_f32_32x32x16_bf16(a0, b0, acc[0][0], 0,0,0);
      acc[0][1] = __builtin_amdgcn_mfma_f32_32x32x16_bf16(a0, b1, acc[0][1], 0,0,0);
      acc[1][0] = __builtin_amdgcn_mfma_f32_32x32x16_bf16(a1, b0, acc[1][0], 0,0,0);
      acc[1][1] = __builtin_amdgcn_mfma_f32_32x32x16_bf16(a1, b1, acc[1][1], 0,0,0);
    }
  }

  const float* bias = mat==0 ? bq : (mat==1 ? bk : bv);
  const float bsc = (mat==0) ? 0.09016844005556021f : 1.0f;   // W pre-scaled; bias scaled here
  float bb_[2];
  #pragma unroll
  for (int ntl=0; ntl<2; ++ntl) bb_[ntl] = bias[cb + nh + ntl*32 + l31] * bsc;

  if (mat <= 1) {
    #pragma unroll
    for (int mt=0; mt<2; ++mt)
      #pragma unroll
      for (int ntl=0; ntl<2; ++ntl)
        #pragma unroll
        for (int r=0; r<16; ++r) {
          int gm = m0 + mh + mt*32 + (r&3) + 8*(r>>2) + 4*h;
          int col = cb + nh + ntl*32 + l31;
          u16 val = f2bf(acc[mt][ntl][r] + bb_[ntl]);
          if (mat == 0) {
            Qb[(size_t)gm*QSTR + col] = val;
          } else {
            int bb2 = gm >> 12, s = gm & (S-1);
            Kt[(size_t)(bb2*128 + (s>>5))*KT_TILE + (s&31)*280 + col] = val;
          }
        }
  } else {
    // V: transpose via LDS, store to Vt tiled [b][t32][e][40]
    __syncthreads();   // T overwrites buf1 region other waves may still be reading
    u16* T = (u16*)smem;     // [128 e][136] = 34816 B (fits 64KB)
    #pragma unroll
    for (int mt=0; mt<2; ++mt)
      #pragma unroll
      for (int ntl=0; ntl<2; ++ntl)
        #pragma unroll
        for (int r=0; r<16; ++r) {
          int e_loc = nh + ntl*32 + l31;
          int m_loc = mh + mt*32 + (r&3) + 8*(r>>2) + 4*h;
          T[(size_t)e_loc*136 + m_loc] = f2bf(acc[mt][ntl][r] + bb_[ntl]);
        }
    __syncthreads();
    int e_loc = tid >> 1, shalf = (tid & 1)*64;
    int e = cb + e_loc;
    #pragma unroll
    for (int g2 = 0; g2 < 2; ++g2) {
      int gm = m0 + shalf + g2*32;
      int bb2 = gm >> 12, s = gm & (S-1);
      u16* dst = Vt + (size_t)(bb2*128 + (s>>5))*VT_TILE + (size_t)e*40;
      const u16* src = T + (size_t)e_loc*136 + shalf + g2*32;
      #pragma unroll
      for (int k2=0;k2<4;++k2) *(uint4*)(dst + k2*8) = *(const uint4*)(src + k2*8);
    }
  }
}

// ---------------- attention: BK=32, async dbuf (K AND V via global_load_lds) ----------------
// [FROZEN at R9: 84.7us, MfmaUtil 35.5, no spill. R5/R8 showed any +16-reg change spills.]
__global__ __launch_bounds__(256, 2) void msp_attn(
    const u16* __restrict__ Qb, const u16* __restrict__ Kt,
    const u16* __restrict__ Vt, float* __restrict__ out,
    float* __restrict__ P1, float* __restrict__ P23,
    float* __restrict__ Lacc)
{
  __shared__ __align__(16) unsigned char smem[77824];  // K dbuf 2x18432 | V dbuf 2x20480

  const int tid = threadIdx.x;
  const int w = tid >> 6, lane = tid & 63;
  const int l31 = lane & 31, h = lane >> 5;

  // XCD-swizzled decode over 512 blocks: 32 qt-blocks sharing (b,tq) land on one XCD
  const int xg = blockIdx.x;
  const int xcd = xg & 7, j = xg >> 3;
  const int c = xcd*2 + (j & 1);
  const int qt = j >> 1;
  const int b = c >> 2, tq = c & 3;
  const int q0 = qt * 128;
  const int qw = q0 + w*32;

  // Q fragments (B-operand): lane holds Q[qw+l31][16*s2 + 8h + j]
  bf16x8 qf[17];
  {
    const u16* qp = Qb + ((size_t)b*S + qw + l31)*QSTR + h*8;
    #pragma unroll
    for (int s2=0; s2<17; ++s2) qf[s2] = *(const bf16x8*)(qp + s2*16);
  }

  const int tIdx0 = b*128 + tq*32;

  f32x16 oacc[8];
  #pragma unroll
  for (int e=0;e<8;++e)
    #pragma unroll
    for (int i=0;i<16;++i) oacc[e][i] = 0.f;
  float l_acc = 0.f;

  { // prologue: K[0] -> k0
    const u16* kg = Kt + (size_t)tIdx0*KT_TILE;
    u16* kl = (u16*)smem;
    #pragma unroll
    for (int i = w; i < 18; i += 4) gl_lds16(kg + i*512 + lane*8, kl + i*512);
  }

  bf16x8 pf[2];   // carried P^T fragments (softmax computed pre-barrier)

  { // peeled it = 0: stage K[1]->k1 + V[0]->v0; QK[0] from k0; softmax[0] pre-barrier
    __syncthreads();
    const u16* kg = Kt + (size_t)(tIdx0 + 1)*KT_TILE;
    u16* kl = (u16*)(smem + 18432);
    #pragma unroll
    for (int i = w; i < 18; i += 4) gl_lds16(kg + i*512 + lane*8, kl + i*512);
    const u16* vg = Vt + (size_t)tIdx0*VT_TILE;
    u16* vl = (u16*)(smem + 36864);
    #pragma unroll
    for (int i = w; i < 20; i += 4) gl_lds16(vg + i*512 + lane*8, vl + i*512);

    const u16* Kp = (const u16*)smem + (size_t)l31*280 + h*8;
    f32x16 sa;
    #pragma unroll
    for (int i=0;i<16;++i) sa[i] = 0.f;
    __builtin_amdgcn_s_setprio(1);
    #pragma unroll
    for (int s2 = 0; s2 < 17; ++s2) {
      bf16x8 kf = *(const bf16x8*)(Kp + s2*16);
      sa = __builtin_amdgcn_mfma_f32_32x32x16_bf16(kf, qf[s2], sa, 0,0,0);
    }
    __builtin_amdgcn_s_setprio(0);
    softmax_pf(sa, h, l_acc, pf);      // pre-barrier: overlaps DMA drain
  }

  for (int it = 1; it < 32; ++it) {
    const int p = it & 1;
    __syncthreads();            // drains K[it] (-> k[p]) and V[it-1] (-> v[p^1])

    if (it < 31) {              // stage K[it+1] -> k[p^1]
      const u16* kg = Kt + (size_t)(tIdx0 + it + 1)*KT_TILE;
      u16* kl = (u16*)(smem + (p^1)*18432);
      #pragma unroll
      for (int i = w; i < 18; i += 4) gl_lds16(kg + i*512 + lane*8, kl + i*512);
    }
    {                           // stage V[it] -> v[p]
      const u16* vg = Vt + (size_t)(tIdx0 + it)*VT_TILE;
      u16* vl = (u16*)(smem + 36864 + p*20480);
      #pragma unroll
      for (int i = w; i < 20; i += 4) gl_lds16(vg + i*512 + lane*8, vl + i*512);
    }

    // QK[it] (chain sa) interleaved with PV[it-1] (carried pf, independent accumulators)
    const u16* Kp = (const u16*)(smem + p*18432) + (size_t)l31*280 + h*8;
    const u16* Vp = (const u16*)(smem + 36864 + (p^1)*20480) + (size_t)l31*40 + h*8;
    f32x16 sa;
    #pragma unroll
    for (int i=0;i<16;++i) sa[i] = 0.f;
    __builtin_amdgcn_s_setprio(1);
    #pragma unroll
    for (int s2 = 0; s2 < 17; ++s2) {
      bf16x8 kf = *(const bf16x8*)(Kp + s2*16);
      sa = __builtin_amdgcn_mfma_f32_32x32x16_bf16(kf, qf[s2], sa, 0,0,0);
      if (s2 < 16) {
        const u16* vb = Vp + (s2>>1)*(32*40) + (s2&1)*16;
        oacc[s2>>1] = __builtin_amdgcn_mfma_f32_32x32x16_bf16(*(const bf16x8*)vb, pf[s2&1], oacc[s2>>1], 0,0,0);
      }
    }
    __builtin_amdgcn_s_setprio(0);

    // softmax[it] pre-barrier -> new pf (old pf consumed by the PV MFMAs above)
    softmax_pf(sa, h, l_acc, pf);
  }

  // tail: l-reduce, then PV[31] from v[1] with the carried pf
  float l_tot = l_acc + __shfl_xor(l_acc, 32, 64);
  if (h == 0) unsafeAtomicAdd(&Lacc[(size_t)b*S + qw + l31], l_tot);

  __syncthreads();              // drain V[31] (staged during it=31 into v[1])
  {
    const u16* Vp = (const u16*)(smem + 36864 + 20480) + (size_t)l31*40 + h*8;
    __builtin_amdgcn_s_setprio(1);
    #pragma unroll
    for (int et = 0; et < 8; ++et) {
      const u16* vb = Vp + et*32*40;
      oacc[et] = __builtin_amdgcn_mfma_f32_32x32x16_bf16(*(const bf16x8*)(vb),      pf[0], oacc[et], 0,0,0);
      oacc[et] = __builtin_amdgcn_mfma_f32_32x32x16_bf16(*(const bf16x8*)(vb + 16), pf[1], oacc[et], 0,0,0);
    }
    __builtin_amdgcn_s_setprio(0);
  }

  // transpose O^T -> O via LDS (2 double-width rounds), STREAMING float4 stores:
  // unique writer per (tq, b, q-row) -> no atomics, no RMW traffic
  float* dst = (tq == 0) ? (out + (size_t)b*S*D)
             : (tq == 1) ? (P1 + (size_t)b*S*D)
                         : (P23 + ((size_t)(tq-2)*4 + b)*S*D);
  float* OflA = (float*)smem;            // [32 q][260]
  float* OflB = (float*)smem + 8320;     // second buffer
  for (int rr = 0; rr < 2; ++rr) {
    __syncthreads();
    if ((w >> 1) == rr) {
      float* Of = (w & 1) ? OflB : OflA;
      #pragma unroll
      for (int et=0; et<8; ++et)
        #pragma unroll
        for (int g=0; g<4; ++g) {
          float4 v4 = { oacc[et][4*g+0], oacc[et][4*g+1], oacc[et][4*g+2], oacc[et][4*g+3] };
          *(float4*)&Of[(size_t)l31*260 + et*32 + 8*g + 4*h] = v4;
        }
    }
    __syncthreads();
    #pragma unroll
    for (int hf = 0; hf < 2; ++hf) {
      const float* Of = hf ? OflB : OflA;
      float* obase = dst + (size_t)(q0 + (rr*2 + hf)*32)*D;
      #pragma unroll
      for (int q2 = 0; q2 < 8; ++q2) {
        int q = q2*4 + (tid>>6);
        int e4 = (tid & 63)*4;
        *(float4*)(obase + (size_t)q*D + e4) = *(const float4*)&Of[(size_t)q*260 + e4];
      }
    }
  }
}

// ---------------- fused 4-way partial sum + normalize ----------------
__global__ __launch_bounds__(256) void msp_norm(
    float* __restrict__ out, const float* __restrict__ P1,
    const float* __restrict__ P23, const float* __restrict__ L)
{
  constexpr size_t PSZ = (size_t)4*S*D;   // floats per partial set (4 batches)
  int idx = blockIdx.x*256 + threadIdx.x;
  int row = idx >> 6, e0 = (idx & 63)*4;
  size_t off = (size_t)row*256 + e0;
  float inv = 1.0f / L[row];
  float4 v  = *(const float4*)(out + off);
  float4 a  = *(const float4*)(P1  + off);
  float4 b2 = *(const float4*)(P23 + off);
  float4 c2 = *(const float4*)(P23 + PSZ + off);
  v.x = (v.x + a.x + b2.x + c2.x) * inv;
  v.y = (v.y + a.y + b2.y + c2.y) * inv;
  v.z = (v.z + a.z + b2.z + c2.z) * inv;
  v.w = (v.w + a.w + b2.w + c2.w) * inv;
  *(float4*)(out + off) = v;
}

extern "C" void kernel_launch(void* const* d_in, const int* in_sizes, int n_in,
                              void* d_out, int out_size, void* d_ws, size_t ws_size,
                              hipStream_t stream) {
  const float* x    = (const float*)d_in[0];
  const float* Wq   = (const float*)d_in[1];
  const float* bq   = (const float*)d_in[2];
  const float* Wk   = (const float*)d_in[3];
  const float* bk   = (const float*)d_in[4];
  const float* Wv   = (const float*)d_in[5];
  const float* bv   = (const float*)d_in[6];
  const float* beta = (const float*)d_in[7];
  float* out = (float*)d_out;

  char* w = (char*)d_ws;
  u16* xc = (u16*)w;
  float* P1 = (float*)w;                            // overlays xc (dead after proj)
  w += (size_t)16384*512*2;                         // 16.8 MB
  u16* Wc = (u16*)w;  w += (size_t)768*512*2;       // 0.79 MB
  u16* Qb = (u16*)w;  w += (size_t)16384*QSTR*2;    // 8.9 MB
  u16* Kt = (u16*)w;  w += (size_t)512*KT_TILE*2;   // 9.2 MB (Vt must follow: junk-tail reads)
  u16* Vt = (u16*)w;  w += (size_t)512*VT_TILE*2;   // 10.5 MB
  float* Lacc = (float*)w; w += (size_t)16384*4;    // 64 KB
  float* P23 = (float*)w;                           // 2 x 16.8 MB

  msp_prep<<<2209, 256, 0, stream>>>(x, Wq, Wk, Wv, beta, xc, Wc, Qb, Kt, Lacc);
  msp_proj<<<dim3(128, 6), 256, 0, stream>>>(xc, Wc, bq, bk, bv, Qb, Kt, Vt);
  msp_attn<<<512, 256, 0, stream>>>(Qb, Kt, Vt, out, P1, P23, Lacc);
  msp_norm<<<4096, 256, 0, stream>>>(out, P1, P23, Lacc);
}

// Round 11
// 188.744 us; speedup vs baseline: 1.2406x; 1.0219x over previous
//
#include <hip/hip_runtime.h>
#include <math.h>
#include <stdint.h>

#define DEV static __device__ __forceinline__
typedef unsigned short u16;

constexpr int D = 256;
constexpr int S = 4096;
constexpr int QSTR = 272;            // Qb row: 256 data + 12 bias-ext + 4 zero
constexpr int KT_TILE = 8960;        // u16: 32 rows x 280
constexpr int VT_TILE = 10240;       // u16: 256 e-rows x 40 (padded for LDS bank spread)

typedef short bf16x8 __attribute__((ext_vector_type(8)));
typedef float f32x16 __attribute__((ext_vector_type(16)));

// RNE f32->bf16 via native convert (v_cvt_pk_bf16_f32)
DEV u16 f2bf(float f){ __bf16 b = (__bf16)f; return __builtin_bit_cast(u16, b); }
DEV float bf2f(u16 h){ return __uint_as_float(((unsigned)h)<<16); }
DEV int packbf(float lo, float hi){ return (int)((((unsigned)f2bf(hi)) << 16) | (unsigned)f2bf(lo)); }
DEV float bfsum2(int d){
  return __uint_as_float(((unsigned)d)<<16) + __uint_as_float(((unsigned)d) & 0xffff0000u);
}
DEV float ex2(float x){ return __builtin_amdgcn_exp2f(x); }   // v_exp_f32 (2^x native)
DEV void gl_lds16(const u16* g, u16* l) {
  __builtin_amdgcn_global_load_lds(
      (const __attribute__((address_space(1))) unsigned int*)g,
      (__attribute__((address_space(3))) unsigned int*)l, 16, 0, 0);
}

// xc/Wc chunk-major + XOR-swizzled 16B-slot addressing (rule #21: linear gl_lds dest,
// inverse-swizzled SOURCE written by prep, swizzled ds_read in proj).
// Chunk = [128 rows][64 u16] = 16KB contiguous; slot j = 16B granule (8 u16).
DEV size_t cm_addr(int rowblock, int chunk, int row_in, int j) {
  return ((size_t)rowblock*8 + chunk)*8192 + (size_t)(((row_in<<3) + j) ^ (row_in & 7))*8;
}
DEV const u16* swz(const u16* base, int row, int slot) {
  return base + ((((row<<3) + slot) ^ (row & 7)) << 3);
}

// softmax of one tile's scores (exp2 domain; log2e pre-folded into Q/bias)
// -> P^T B-fragments + running l. Called at the END of each iteration (pre-barrier):
// overlaps other waves' MFMA phase + the DMA drain; carries pf (8 regs) not sc (16).
DEV void softmax_pf(const f32x16& s, int h, float& l_acc, bf16x8* pf) {
  #pragma unroll
  for (int s2 = 0; s2 < 2; ++s2) {
    float e0 = ex2(s[8*s2+0]), e1 = ex2(s[8*s2+1]);
    float e2 = ex2(s[8*s2+2]), e3 = ex2(s[8*s2+3]);
    float e4 = ex2(s[8*s2+4]), e5 = ex2(s[8*s2+5]);
    float e6 = ex2(s[8*s2+6]), e7 = ex2(s[8*s2+7]);
    int P0d0 = packbf(e0, e1), P0d1 = packbf(e2, e3);
    int P1d0 = packbf(e4, e5), P1d1 = packbf(e6, e7);
    // l sums the bf16-ROUNDED p so normalization cancels rounding bias
    l_acc += bfsum2(P0d0) + bfsum2(P0d1) + bfsum2(P1d0) + bfsum2(P1d1);
    int s0 = h ? P0d0 : P1d0;
    int s1 = h ? P0d1 : P1d1;
    int r0 = __shfl_xor(s0, 32, 64);
    int r1 = __shfl_xor(s1, 32, 64);
    union { int d[4]; bf16x8 v; } u;
    u.d[0] = h ? r0 : P0d0;
    u.d[1] = h ? r1 : P0d1;
    u.d[2] = h ? P1d0 : r0;
    u.d[3] = h ? P1d1 : r1;
    pf[s2] = u.v;
  }
}

// ---------------- prep: hi/lo split (chunk-major swizzled layouts), bias-ext, zero Lacc ----
__global__ __launch_bounds__(256) void msp_prep(
    const float* __restrict__ x, const float* __restrict__ Wq,
    const float* __restrict__ Wk, const float* __restrict__ Wv,
    const float* __restrict__ beta,
    u16* __restrict__ xc, u16* __restrict__ Wc,
    u16* __restrict__ Qb, u16* __restrict__ Kt,
    float* __restrict__ Lacc)
{
  const int blk = blockIdx.x, tid = threadIdx.x;
  if (blk < 2048) {                       // xc: hi in chunks 0..3, lo in chunks 4..7
    int row = blk*8 + (tid>>5);
    int col = (tid&31)*8;
    const float* p = x + (size_t)row*256 + col;
    union { u16 s[8]; uint4 v; } hh, ll;
    #pragma unroll
    for (int i=0;i<8;++i){ float v = p[i]; u16 h2 = f2bf(v); hh.s[i]=h2; ll.s[i]=f2bf(v - bf2f(h2)); }
    int rb = row >> 7, rin = row & 127;
    int ch = col >> 6, j = (col >> 3) & 7;
    *(uint4*)(xc + cm_addr(rb, ch,     rin, j)) = hh.v;
    *(uint4*)(xc + cm_addr(rb, ch + 4, rin, j)) = ll.v;
  } else if (blk < 2144) {                // Wc rows: [0,256)=Wq*log2e/16, [256,512)=Wk, [512,768)=Wv
    int q = blk - 2048;                   // 96 blocks
    int mat = q >> 5;
    int idx = (q & 31)*2048 + tid*8;      // 0..65535
    int o = idx >> 8, cc = idx & 255;
    const float* W = mat==0 ? Wq : (mat==1 ? Wk : Wv);
    float sc = (mat==0) ? 0.09016844005556021f : 1.0f;   // (1/16)*log2(e) folded on Q side
    const float* p = W + (size_t)o*256 + cc;
    union { u16 s[8]; uint4 v; } hh, ll;
    #pragma unroll
    for (int i=0;i<8;++i){ float v = p[i]*sc; u16 h2 = f2bf(v); hh.s[i]=h2; ll.s[i]=f2bf(v - bf2f(h2)); }
    int rowg = mat*256 + o;
    int rb = rowg >> 7, rin = rowg & 127;
    int ch = cc >> 6, j = (cc >> 3) & 7;
    *(uint4*)(Wc + cm_addr(rb, ch,     rin, j)) = hh.v;
    *(uint4*)(Wc + cm_addr(rb, ch + 4, rin, j)) = ll.v;
  } else if (blk < 2208) {                // bias-ext cols (64 blocks)
    int row = (blk - 2144)*256 + tid;     // b*4096 + s
    int s = row & (S-1);
    int bb = row >> 12;
    constexpr float L2E = 1.4426950408889634f;
    float b0 = beta[0]*L2E, b1 = beta[1]*L2E;   // exp2-domain: log2e on Q side
    int i24 = s % 24, i720 = s % 720;
    float t0 = (float)i24  * 0.26179938779914944f;    // 2pi/24
    float t1 = (float)i720 * 0.008726646259971648f;   // 2pi/720
    float c0 = cosf(t0), s0 = sinf(t0), c1 = cosf(t1), s1 = sinf(t1);
    float qv[4] = {b0*c0, b0*s0, b1*c1, b1*s1};   // beta folded on Q side
    float kv[4] = {c0, s0, c1, s1};
    u16* qp = Qb + (size_t)row*QSTR + 256;
    u16* kp = Kt + (size_t)(bb*128 + (s>>5))*KT_TILE + (s&31)*280 + 256;
    #pragma unroll
    for (int n=0;n<4;++n){
      u16 uh = f2bf(qv[n]); u16 ul = f2bf(qv[n]-bf2f(uh));
      u16 vh = f2bf(kv[n]); u16 vl = f2bf(kv[n]-bf2f(vh));
      // dot over triplet = uh*vh + uh*vl + ul*vh ~= u*v (drops ul*vl <= 2^-18)
      qp[n*3+0]=uh; qp[n*3+1]=uh; qp[n*3+2]=ul;
      kp[n*3+0]=vh; kp[n*3+1]=vl; kp[n*3+2]=vh;
    }
    #pragma unroll
    for (int c=12;c<16;++c){ qp[c]=0; kp[c]=0; }
  } else {                                // zero Lacc (16384 f32)
    float4* p = (float4*)Lacc;
    float4 z = {0.f,0.f,0.f,0.f};
    #pragma unroll
    for (int c=0;c<16;++c) p[tid + c*256] = z;
  }
}

// ---------------- fused projection GEMM: C[16384x768] = xc . Wc^T, route Q/K/V ----------------
// Staging via global_load_lds (1024B coalesced DMA) from chunk-major pre-swizzled xc/Wc;
// ds_reads apply the XOR -> conflict-free, no register round-trip. [R10: verified, ~-10us]
__global__ __launch_bounds__(256, 2) void msp_proj(
    const u16* __restrict__ xc, const u16* __restrict__ Wc,
    const float* __restrict__ bq, const float* __restrict__ bk, const float* __restrict__ bv,
    u16* __restrict__ Qb, u16* __restrict__ Kt, u16* __restrict__ Vt)
{
  __shared__ __align__(16) u16 smem[2][2][128][64];   // [buf][A/B][row][64] = 65536 B, swizzled

  const int tid = threadIdx.x;
  const int w = tid >> 6, lane = tid & 63;
  const int l31 = lane & 31, h = lane >> 5;
  const int m0 = blockIdx.x * 128;
  const int nblk = blockIdx.y;
  const int mat = nblk >> 1, cb = (nblk & 1) * 128;
  const int mh = (w & 1) * 64, nh = (w >> 1) * 64;

  const u16* Ag = xc + (size_t)blockIdx.x*8*8192;   // + kc8*8192
  const u16* Bg = Wc + (size_t)nblk*8*8192;

  { // prologue: chunk 0 -> buf 0 (async DMA)
    #pragma unroll
    for (int i = w; i < 16; i += 4) gl_lds16(Ag + i*512 + lane*8, &smem[0][0][0][0] + i*512);
    #pragma unroll
    for (int i = w; i < 16; i += 4) gl_lds16(Bg + i*512 + lane*8, &smem[0][1][0][0] + i*512);
  }

  f32x16 acc[2][2];
  #pragma unroll
  for (int a=0;a<2;++a)
    #pragma unroll
    for (int c=0;c<2;++c)
      #pragma unroll
      for (int i=0;i<16;++i) acc[a][c][i] = 0.f;

  for (int kc8 = 0; kc8 < 8; ++kc8) {
    __syncthreads();            // drains chunk kc8 into buf p
    const int p = kc8 & 1;
    if (kc8 < 7) {              // stage chunk kc8+1 -> buf p^1
      const u16* a2 = Ag + (size_t)(kc8+1)*8192;
      const u16* b2 = Bg + (size_t)(kc8+1)*8192;
      #pragma unroll
      for (int i = w; i < 16; i += 4) gl_lds16(a2 + i*512 + lane*8, &smem[p^1][0][0][0] + i*512);
      #pragma unroll
      for (int i = w; i < 16; i += 4) gl_lds16(b2 + i*512 + lane*8, &smem[p^1][1][0][0] + i*512);
    }
    const u16* As = &smem[p][0][0][0];
    const u16* Bs = &smem[p][1][0][0];
    #pragma unroll
    for (int kf = 0; kf < 4; ++kf) {
      const int slot = kf*2 + h;
      bf16x8 a0 = *(const bf16x8*)swz(As, mh + l31, slot);
      bf16x8 a1 = *(const bf16x8*)swz(As, mh + 32 + l31, slot);
      bf16x8 b0 = *(const bf16x8*)swz(Bs, nh + l31, slot);
      bf16x8 b1 = *(const bf16x8*)swz(Bs, nh + 32 + l31, slot);
      acc[0][0] = __builtin_amdgcn_mfma_f32_32x32x16_bf16(a0, b0, acc[0][0], 0,0,0);
      acc[0][1] = __builtin_amdgcn_mfma_f32_32x32x16_bf16(a0, b1, acc[0][1], 0,0,0);
      acc[1][0] = __builtin_amdgcn_mfma_f32_32x32x16_bf16(a1, b0, acc[1][0], 0,0,0);
      acc[1][1] = __builtin_amdgcn_mfma_f32_32x32x16_bf16(a1, b1, acc[1][1], 0,0,0);
    }
  }

  const float* bias = mat==0 ? bq : (mat==1 ? bk : bv);
  const float bsc = (mat==0) ? 0.09016844005556021f : 1.0f;   // W pre-scaled; bias scaled here
  float bb_[2];
  #pragma unroll
  for (int ntl=0; ntl<2; ++ntl) bb_[ntl] = bias[cb + nh + ntl*32 + l31] * bsc;

  if (mat <= 1) {
    #pragma unroll
    for (int mt=0; mt<2; ++mt)
      #pragma unroll
      for (int ntl=0; ntl<2; ++ntl)
        #pragma unroll
        for (int r=0; r<16; ++r) {
          int gm = m0 + mh + mt*32 + (r&3) + 8*(r>>2) + 4*h;
          int col = cb + nh + ntl*32 + l31;
          u16 val = f2bf(acc[mt][ntl][r] + bb_[ntl]);
          if (mat == 0) {
            Qb[(size_t)gm*QSTR + col] = val;
          } else {
            int bb2 = gm >> 12, s = gm & (S-1);
            Kt[(size_t)(bb2*128 + (s>>5))*KT_TILE + (s&31)*280 + col] = val;
          }
        }
  } else {
    // V: transpose via LDS, store to Vt tiled [b][t32][e][40]
    __syncthreads();   // T overwrites buf region other waves may still be reading
    u16* T = (u16*)smem;     // [128 e][136] = 34816 B
    #pragma unroll
    for (int mt=0; mt<2; ++mt)
      #pragma unroll
      for (int ntl=0; ntl<2; ++ntl)
        #pragma unroll
        for (int r=0; r<16; ++r) {
          int e_loc = nh + ntl*32 + l31;
          int m_loc = mh + mt*32 + (r&3) + 8*(r>>2) + 4*h;
          T[(size_t)e_loc*136 + m_loc] = f2bf(acc[mt][ntl][r] + bb_[ntl]);
        }
    __syncthreads();
    int e_loc = tid >> 1, shalf = (tid & 1)*64;
    int e = cb + e_loc;
    #pragma unroll
    for (int g2 = 0; g2 < 2; ++g2) {
      int gm = m0 + shalf + g2*32;
      int bb2 = gm >> 12, s = gm & (S-1);
      u16* dst = Vt + (size_t)(bb2*128 + (s>>5))*VT_TILE + (size_t)e*40;
      const u16* src = T + (size_t)e_loc*136 + shalf + g2*32;
      #pragma unroll
      for (int k2=0;k2<4;++k2) *(uint4*)(dst + k2*8) = *(const uint4*)(src + k2*8);
    }
  }
}

// ---------------- attention: QBLK=256, 8 waves, 1 block/CU (halved staging DMA) ------------
// Per-wave code identical to the R9 83.5us kernel; the K/V tile pair is now staged ONCE per
// CU-iteration (shared by 8 waves) instead of twice (2 blocks x 4 waves). Staging DMA and
// vmcnt drain halve; registers/wave, LDS bytes, and ds_read count unchanged.
__global__ __launch_bounds__(512, 2) void msp_attn(
    const u16* __restrict__ Qb, const u16* __restrict__ Kt,
    const u16* __restrict__ Vt, float* __restrict__ out,
    float* __restrict__ P1, float* __restrict__ P23,
    float* __restrict__ Lacc)
{
  __shared__ __align__(16) unsigned char smem[77824];  // K dbuf 2x18432 | V dbuf 2x20480

  const int tid = threadIdx.x;
  const int w = tid >> 6, lane = tid & 63;
  const int l31 = lane & 31, h = lane >> 5;

  // XCD-swizzled decode over 256 blocks: 16 qt-blocks sharing (b,tq) land on one XCD
  const int xg = blockIdx.x;
  const int xcd = xg & 7, j = xg >> 3;         // j in 0..31
  const int c = xcd*2 + (j & 1);               // (b,tq) index 0..15
  const int qt = j >> 1;                       // 0..15
  const int b = c >> 2, tq = c & 3;
  const int q0 = qt * 256;
  const int qw = q0 + w*32;

  // Q fragments (B-operand): lane holds Q[qw+l31][16*s2 + 8h + j]
  bf16x8 qf[17];
  {
    const u16* qp = Qb + ((size_t)b*S + qw + l31)*QSTR + h*8;
    #pragma unroll
    for (int s2=0; s2<17; ++s2) qf[s2] = *(const bf16x8*)(qp + s2*16);
  }

  const int tIdx0 = b*128 + tq*32;

  f32x16 oacc[8];
  #pragma unroll
  for (int e=0;e<8;++e)
    #pragma unroll
    for (int i=0;i<16;++i) oacc[e][i] = 0.f;
  float l_acc = 0.f;

  { // prologue: K[0] -> k0
    const u16* kg = Kt + (size_t)tIdx0*KT_TILE;
    u16* kl = (u16*)smem;
    #pragma unroll
    for (int i = w; i < 18; i += 8) gl_lds16(kg + i*512 + lane*8, kl + i*512);
  }

  bf16x8 pf[2];   // carried P^T fragments (softmax computed pre-barrier)

  { // peeled it = 0: stage K[1]->k1 + V[0]->v0; QK[0] from k0; softmax[0] pre-barrier
    __syncthreads();
    const u16* kg = Kt + (size_t)(tIdx0 + 1)*KT_TILE;
    u16* kl = (u16*)(smem + 18432);
    #pragma unroll
    for (int i = w; i < 18; i += 8) gl_lds16(kg + i*512 + lane*8, kl + i*512);
    const u16* vg = Vt + (size_t)tIdx0*VT_TILE;
    u16* vl = (u16*)(smem + 36864);
    #pragma unroll
    for (int i = w; i < 20; i += 8) gl_lds16(vg + i*512 + lane*8, vl + i*512);

    const u16* Kp = (const u16*)smem + (size_t)l31*280 + h*8;
    f32x16 sa;
    #pragma unroll
    for (int i=0;i<16;++i) sa[i] = 0.f;
    __builtin_amdgcn_s_setprio(1);
    #pragma unroll
    for (int s2 = 0; s2 < 17; ++s2) {
      bf16x8 kf = *(const bf16x8*)(Kp + s2*16);
      sa = __builtin_amdgcn_mfma_f32_32x32x16_bf16(kf, qf[s2], sa, 0,0,0);
    }
    __builtin_amdgcn_s_setprio(0);
    softmax_pf(sa, h, l_acc, pf);      // pre-barrier: overlaps DMA drain
  }

  for (int it = 1; it < 32; ++it) {
    const int p = it & 1;
    __syncthreads();            // drains K[it] (-> k[p]) and V[it-1] (-> v[p^1])

    if (it < 31) {              // stage K[it+1] -> k[p^1]
      const u16* kg = Kt + (size_t)(tIdx0 + it + 1)*KT_TILE;
      u16* kl = (u16*)(smem + (p^1)*18432);
      #pragma unroll
      for (int i = w; i < 18; i += 8) gl_lds16(kg + i*512 + lane*8, kl + i*512);
    }
    {                           // stage V[it] -> v[p]
      const u16* vg = Vt + (size_t)(tIdx0 + it)*VT_TILE;
      u16* vl = (u16*)(smem + 36864 + p*20480);
      #pragma unroll
      for (int i = w; i < 20; i += 8) gl_lds16(vg + i*512 + lane*8, vl + i*512);
    }

    // QK[it] (chain sa) interleaved with PV[it-1] (carried pf, independent accumulators)
    const u16* Kp = (const u16*)(smem + p*18432) + (size_t)l31*280 + h*8;
    const u16* Vp = (const u16*)(smem + 36864 + (p^1)*20480) + (size_t)l31*40 + h*8;
    f32x16 sa;
    #pragma unroll
    for (int i=0;i<16;++i) sa[i] = 0.f;
    __builtin_amdgcn_s_setprio(1);
    #pragma unroll
    for (int s2 = 0; s2 < 17; ++s2) {
      bf16x8 kf = *(const bf16x8*)(Kp + s2*16);
      sa = __builtin_amdgcn_mfma_f32_32x32x16_bf16(kf, qf[s2], sa, 0,0,0);
      if (s2 < 16) {
        const u16* vb = Vp + (s2>>1)*(32*40) + (s2&1)*16;
        oacc[s2>>1] = __builtin_amdgcn_mfma_f32_32x32x16_bf16(*(const bf16x8*)vb, pf[s2&1], oacc[s2>>1], 0,0,0);
      }
    }
    __builtin_amdgcn_s_setprio(0);

    // softmax[it] pre-barrier -> new pf (old pf consumed by the PV MFMAs above)
    softmax_pf(sa, h, l_acc, pf);
  }

  // tail: l-reduce, then PV[31] from v[1] with the carried pf
  float l_tot = l_acc + __shfl_xor(l_acc, 32, 64);
  if (h == 0) unsafeAtomicAdd(&Lacc[(size_t)b*S + qw + l31], l_tot);

  __syncthreads();              // drain V[31] (staged during it=31 into v[1])
  {
    const u16* Vp = (const u16*)(smem + 36864 + 20480) + (size_t)l31*40 + h*8;
    __builtin_amdgcn_s_setprio(1);
    #pragma unroll
    for (int et = 0; et < 8; ++et) {
      const u16* vb = Vp + et*32*40;
      oacc[et] = __builtin_amdgcn_mfma_f32_32x32x16_bf16(*(const bf16x8*)(vb),      pf[0], oacc[et], 0,0,0);
      oacc[et] = __builtin_amdgcn_mfma_f32_32x32x16_bf16(*(const bf16x8*)(vb + 16), pf[1], oacc[et], 0,0,0);
    }
    __builtin_amdgcn_s_setprio(0);
  }

  // transpose O^T -> O via LDS: 4 rounds, 2 waves each (A/B buffers), STREAMING float4
  // stores; unique writer per (tq, b, q-row) -> no atomics
  float* dst = (tq == 0) ? (out + (size_t)b*S*D)
             : (tq == 1) ? (P1 + (size_t)b*S*D)
                         : (P23 + ((size_t)(tq-2)*4 + b)*S*D);
  float* OflA = (float*)smem;            // [32 q][260]
  float* OflB = (float*)smem + 8320;     // second buffer
  for (int rr = 0; rr < 4; ++rr) {
    __syncthreads();
    if ((w >> 1) == rr) {
      float* Of = (w & 1) ? OflB : OflA;
      #pragma unroll
      for (int et=0; et<8; ++et)
        #pragma unroll
        for (int g=0; g<4; ++g) {
          float4 v4 = { oacc[et][4*g+0], oacc[et][4*g+1], oacc[et][4*g+2], oacc[et][4*g+3] };
          *(float4*)&Of[(size_t)l31*260 + et*32 + 8*g + 4*h] = v4;
        }
    }
    __syncthreads();
    #pragma unroll
    for (int hf = 0; hf < 2; ++hf) {
      const float* Of = hf ? OflB : OflA;
      float* obase = dst + (size_t)(q0 + rr*64 + hf*32)*D;
      #pragma unroll
      for (int q2 = 0; q2 < 4; ++q2) {
        int q = q2*8 + (tid>>6);
        int e4 = (tid & 63)*4;
        *(float4*)(obase + (size_t)q*D + e4) = *(const float4*)&Of[(size_t)q*260 + e4];
      }
    }
  }
}

// ---------------- fused 4-way partial sum + normalize ----------------
__global__ __launch_bounds__(256) void msp_norm(
    float* __restrict__ out, const float* __restrict__ P1,
    const float* __restrict__ P23, const float* __restrict__ L)
{
  constexpr size_t PSZ = (size_t)4*S*D;   // floats per partial set (4 batches)
  int idx = blockIdx.x*256 + threadIdx.x;
  int row = idx >> 6, e0 = (idx & 63)*4;
  size_t off = (size_t)row*256 + e0;
  float inv = 1.0f / L[row];
  float4 v  = *(const float4*)(out + off);
  float4 a  = *(const float4*)(P1  + off);
  float4 b2 = *(const float4*)(P23 + off);
  float4 c2 = *(const float4*)(P23 + PSZ + off);
  v.x = (v.x + a.x + b2.x + c2.x) * inv;
  v.y = (v.y + a.y + b2.y + c2.y) * inv;
  v.z = (v.z + a.z + b2.z + c2.z) * inv;
  v.w = (v.w + a.w + b2.w + c2.w) * inv;
  *(float4*)(out + off) = v;
}

extern "C" void kernel_launch(void* const* d_in, const int* in_sizes, int n_in,
                              void* d_out, int out_size, void* d_ws, size_t ws_size,
                              hipStream_t stream) {
  const float* x    = (const float*)d_in[0];
  const float* Wq   = (const float*)d_in[1];
  const float* bq   = (const float*)d_in[2];
  const float* Wk   = (const float*)d_in[3];
  const float* bk   = (const float*)d_in[4];
  const float* Wv   = (const float*)d_in[5];
  const float* bv   = (const float*)d_in[6];
  const float* beta = (const float*)d_in[7];
  float* out = (float*)d_out;

  char* w = (char*)d_ws;
  u16* xc = (u16*)w;
  float* P1 = (float*)w;                            // overlays xc (dead after proj)
  w += (size_t)16384*512*2;                         // 16.8 MB
  u16* Wc = (u16*)w;  w += (size_t)768*512*2;       // 0.79 MB
  u16* Qb = (u16*)w;  w += (size_t)16384*QSTR*2;    // 8.9 MB
  u16* Kt = (u16*)w;  w += (size_t)512*KT_TILE*2;   // 9.2 MB (Vt must follow: junk-tail reads)
  u16* Vt = (u16*)w;  w += (size_t)512*VT_TILE*2;   // 10.5 MB
  float* Lacc = (float*)w; w += (size_t)16384*4;    // 64 KB
  float* P23 = (float*)w;                           // 2 x 16.8 MB

  msp_prep<<<2209, 256, 0, stream>>>(x, Wq, Wk, Wv, beta, xc, Wc, Qb, Kt, Lacc);
  msp_proj<<<dim3(128, 6), 256, 0, stream>>>(xc, Wc, bq, bk, bv, Qb, Kt, Vt);
  msp_attn<<<256, 512, 0, stream>>>(Qb, Kt, Vt, out, P1, P23, Lacc);
  msp_norm<<<4096, 256, 0, stream>>>(out, P1, P23, Lacc);
}

// Round 13
// 179.259 us; speedup vs baseline: 1.3062x; 1.0529x over previous
//
#include <hip/hip_runtime.h>
#include <math.h>
#include <stdint.h>

#define DEV static __device__ __forceinline__
typedef unsigned short u16;

constexpr int D = 256;
constexpr int S = 4096;
constexpr int QSTR = 272;            // Qb row: 256 data + 12 bias-ext + 4 zero
constexpr int KT_TILE = 8960;        // u16: 32 rows x 280
constexpr int VT_TILE = 10240;       // u16: 256 e-rows x 40 (padded for LDS bank spread)

typedef short bf16x8 __attribute__((ext_vector_type(8)));
typedef float f32x16 __attribute__((ext_vector_type(16)));
typedef int v2i __attribute__((ext_vector_type(2)));

// RNE f32->bf16 via native convert (v_cvt_pk_bf16_f32)
DEV u16 f2bf(float f){ __bf16 b = (__bf16)f; return __builtin_bit_cast(u16, b); }
DEV float bf2f(u16 h){ return __uint_as_float(((unsigned)h)<<16); }
DEV int packbf(float lo, float hi){ return (int)((((unsigned)f2bf(hi)) << 16) | (unsigned)f2bf(lo)); }
DEV float bfsum2(int d){
  return __uint_as_float(((unsigned)d)<<16) + __uint_as_float(((unsigned)d) & 0xffff0000u);
}
DEV float ex2(float x){ return __builtin_amdgcn_exp2f(x); }   // v_exp_f32 (2^x native)
DEV void gl_lds16(const u16* g, u16* l) {
  __builtin_amdgcn_global_load_lds(
      (const __attribute__((address_space(1))) unsigned int*)g,
      (__attribute__((address_space(3))) unsigned int*)l, 16, 0, 0);
}

// xc/Wc chunk-major + XOR-swizzled 16B-slot addressing (rule #21: linear gl_lds dest,
// inverse-swizzled SOURCE written by prep, swizzled ds_read in proj).
// Chunk = [128 rows][64 u16] = 16KB contiguous; slot j = 16B granule (8 u16).
// K=256 (hi-only): the old lo-lo half computed eps_x*eps_W ~ 2^-18 relative -- the cross
// terms (first-order bf16 correction) were never computed by the [xh|xl].[Wh|Wl]
// structure anyway, so the lo half was dead weight at half of proj+prep cost.
DEV size_t cm_addr(int rowblock, int chunk, int row_in, int j) {
  return ((size_t)rowblock*4 + chunk)*8192 + (size_t)(((row_in<<3) + j) ^ (row_in & 7))*8;
}
DEV const u16* swz(const u16* base, int row, int slot) {
  return base + ((((row<<3) + slot) ^ (row & 7)) << 3);
}

// softmax of one tile's scores (exp2 domain; log2e pre-folded into Q/bias)
// -> P^T B-fragments + running l. Called at the END of each iteration (pre-barrier).
// Half-exchange via v_permlane32_swap (VALU pipe) instead of ds_bpermute (LDS pipe,
// the binding resource). Semantics: swap(D,S): new_D=[D.lo|S.lo], new_S=[D.hi|S.hi].
// Need r0: lanes<32 get P0.hi, lanes>=32 get P1.lo -> D=P0, S=P1 (R12 had args
// REVERSED -> absmax 0.057; fixed here), r0 = h ? new_D : new_S.
DEV void softmax_pf(const f32x16& s, int h, float& l_acc, bf16x8* pf) {
  #pragma unroll
  for (int s2 = 0; s2 < 2; ++s2) {
    float e0 = ex2(s[8*s2+0]), e1 = ex2(s[8*s2+1]);
    float e2 = ex2(s[8*s2+2]), e3 = ex2(s[8*s2+3]);
    float e4 = ex2(s[8*s2+4]), e5 = ex2(s[8*s2+5]);
    float e6 = ex2(s[8*s2+6]), e7 = ex2(s[8*s2+7]);
    int P0d0 = packbf(e0, e1), P0d1 = packbf(e2, e3);
    int P1d0 = packbf(e4, e5), P1d1 = packbf(e6, e7);
    // l sums the bf16-ROUNDED p so normalization cancels rounding bias
    l_acc += bfsum2(P0d0) + bfsum2(P0d1) + bfsum2(P1d0) + bfsum2(P1d1);
    v2i w0 = __builtin_amdgcn_permlane32_swap(P0d0, P1d0, false, false);
    v2i w1 = __builtin_amdgcn_permlane32_swap(P0d1, P1d1, false, false);
    int r0 = h ? w0.x : w0.y;
    int r1 = h ? w1.x : w1.y;
    union { int d[4]; bf16x8 v; } u;
    u.d[0] = h ? r0 : P0d0;
    u.d[1] = h ? r1 : P0d1;
    u.d[2] = h ? P1d0 : r0;
    u.d[3] = h ? P1d1 : r1;
    pf[s2] = u.v;
  }
}

// ---------------- prep: bf16 convert (chunk-major swizzled layouts), bias-ext, zero Lacc ----
__global__ __launch_bounds__(256) void msp_prep(
    const float* __restrict__ x, const float* __restrict__ Wq,
    const float* __restrict__ Wk, const float* __restrict__ Wv,
    const float* __restrict__ beta,
    u16* __restrict__ xc, u16* __restrict__ Wc,
    u16* __restrict__ Qb, u16* __restrict__ Kt,
    float* __restrict__ Lacc)
{
  const int blk = blockIdx.x, tid = threadIdx.x;
  if (blk < 2048) {                       // xc: 4 chunks/rowblock (hi only)
    int row = blk*8 + (tid>>5);
    int col = (tid&31)*8;
    const float* p = x + (size_t)row*256 + col;
    union { u16 s[8]; uint4 v; } hh;
    #pragma unroll
    for (int i=0;i<8;++i){ hh.s[i] = f2bf(p[i]); }
    int rb = row >> 7, rin = row & 127;
    int ch = col >> 6, j = (col >> 3) & 7;
    *(uint4*)(xc + cm_addr(rb, ch, rin, j)) = hh.v;
  } else if (blk < 2144) {                // Wc rows: [0,256)=Wq*log2e/16, [256,512)=Wk, [512,768)=Wv
    int q = blk - 2048;                   // 96 blocks
    int mat = q >> 5;
    int idx = (q & 31)*2048 + tid*8;      // 0..65535
    int o = idx >> 8, cc = idx & 255;
    const float* W = mat==0 ? Wq : (mat==1 ? Wk : Wv);
    float sc = (mat==0) ? 0.09016844005556021f : 1.0f;   // (1/16)*log2(e) folded on Q side
    const float* p = W + (size_t)o*256 + cc;
    union { u16 s[8]; uint4 v; } hh;
    #pragma unroll
    for (int i=0;i<8;++i){ hh.s[i] = f2bf(p[i]*sc); }
    int rowg = mat*256 + o;
    int rb = rowg >> 7, rin = rowg & 127;
    int ch = cc >> 6, j = (cc >> 3) & 7;
    *(uint4*)(Wc + cm_addr(rb, ch, rin, j)) = hh.v;
  } else if (blk < 2208) {                // bias-ext cols (64 blocks)
    int row = (blk - 2144)*256 + tid;     // b*4096 + s
    int s = row & (S-1);
    int bb = row >> 12;
    constexpr float L2E = 1.4426950408889634f;
    float b0 = beta[0]*L2E, b1 = beta[1]*L2E;   // exp2-domain: log2e on Q side
    int i24 = s % 24, i720 = s % 720;
    float t0 = (float)i24  * 0.26179938779914944f;    // 2pi/24
    float t1 = (float)i720 * 0.008726646259971648f;   // 2pi/720
    float c0 = cosf(t0), s0 = sinf(t0), c1 = cosf(t1), s1 = sinf(t1);
    float qv[4] = {b0*c0, b0*s0, b1*c1, b1*s1};   // beta folded on Q side
    float kv[4] = {c0, s0, c1, s1};
    u16* qp = Qb + (size_t)row*QSTR + 256;
    u16* kp = Kt + (size_t)(bb*128 + (s>>5))*KT_TILE + (s&31)*280 + 256;
    #pragma unroll
    for (int n=0;n<4;++n){
      u16 uh = f2bf(qv[n]); u16 ul = f2bf(qv[n]-bf2f(uh));
      u16 vh = f2bf(kv[n]); u16 vl = f2bf(kv[n]-bf2f(vh));
      // dot over triplet = uh*vh + uh*vl + ul*vh ~= u*v (drops ul*vl <= 2^-18)
      qp[n*3+0]=uh; qp[n*3+1]=uh; qp[n*3+2]=ul;
      kp[n*3+0]=vh; kp[n*3+1]=vl; kp[n*3+2]=vh;
    }
    #pragma unroll
    for (int c=12;c<16;++c){ qp[c]=0; kp[c]=0; }
  } else {                                // zero Lacc (16384 f32)
    float4* p = (float4*)Lacc;
    float4 z = {0.f,0.f,0.f,0.f};
    #pragma unroll
    for (int c=0;c<16;++c) p[tid + c*256] = z;
  }
}

// ---------------- fused projection GEMM: C[16384x768] = xc . Wc^T (K=256), route Q/K/V -------
// Staging via global_load_lds (1024B coalesced DMA) from chunk-major pre-swizzled xc/Wc;
// ds_reads apply the XOR -> conflict-free, no register round-trip. [R10: verified]
__global__ __launch_bounds__(256, 2) void msp_proj(
    const u16* __restrict__ xc, const u16* __restrict__ Wc,
    const float* __restrict__ bq, const float* __restrict__ bk, const float* __restrict__ bv,
    u16* __restrict__ Qb, u16* __restrict__ Kt, u16* __restrict__ Vt)
{
  __shared__ __align__(16) u16 smem[2][2][128][64];   // [buf][A/B][row][64] = 65536 B, swizzled

  const int tid = threadIdx.x;
  const int w = tid >> 6, lane = tid & 63;
  const int l31 = lane & 31, h = lane >> 5;
  const int m0 = blockIdx.x * 128;
  const int nblk = blockIdx.y;
  const int mat = nblk >> 1, cb = (nblk & 1) * 128;
  const int mh = (w & 1) * 64, nh = (w >> 1) * 64;

  const u16* Ag = xc + (size_t)blockIdx.x*4*8192;   // + kc8*8192
  const u16* Bg = Wc + (size_t)nblk*4*8192;

  { // prologue: chunk 0 -> buf 0 (async DMA)
    #pragma unroll
    for (int i = w; i < 16; i += 4) gl_lds16(Ag + i*512 + lane*8, &smem[0][0][0][0] + i*512);
    #pragma unroll
    for (int i = w; i < 16; i += 4) gl_lds16(Bg + i*512 + lane*8, &smem[0][1][0][0] + i*512);
  }

  f32x16 acc[2][2];
  #pragma unroll
  for (int a=0;a<2;++a)
    #pragma unroll
    for (int c=0;c<2;++c)
      #pragma unroll
      for (int i=0;i<16;++i) acc[a][c][i] = 0.f;

  for (int kc8 = 0; kc8 < 4; ++kc8) {
    __syncthreads();            // drains chunk kc8 into buf p
    const int p = kc8 & 1;
    if (kc8 < 3) {              // stage chunk kc8+1 -> buf p^1
      const u16* a2 = Ag + (size_t)(kc8+1)*8192;
      const u16* b2 = Bg + (size_t)(kc8+1)*8192;
      #pragma unroll
      for (int i = w; i < 16; i += 4) gl_lds16(a2 + i*512 + lane*8, &smem[p^1][0][0][0] + i*512);
      #pragma unroll
      for (int i = w; i < 16; i += 4) gl_lds16(b2 + i*512 + lane*8, &smem[p^1][1][0][0] + i*512);
    }
    const u16* As = &smem[p][0][0][0];
    const u16* Bs = &smem[p][1][0][0];
    #pragma unroll
    for (int kf = 0; kf < 4; ++kf) {
      const int slot = kf*2 + h;
      bf16x8 a0 = *(const bf16x8*)swz(As, mh + l31, slot);
      bf16x8 a1 = *(const bf16x8*)swz(As, mh + 32 + l31, slot);
      bf16x8 b0 = *(const bf16x8*)swz(Bs, nh + l31, slot);
      bf16x8 b1 = *(const bf16x8*)swz(Bs, nh + 32 + l31, slot);
      acc[0][0] = __builtin_amdgcn_mfma_f32_32x32x16_bf16(a0, b0, acc[0][0], 0,0,0);
      acc[0][1] = __builtin_amdgcn_mfma_f32_32x32x16_bf16(a0, b1, acc[0][1], 0,0,0);
      acc[1][0] = __builtin_amdgcn_mfma_f32_32x32x16_bf16(a1, b0, acc[1][0], 0,0,0);
      acc[1][1] = __builtin_amdgcn_mfma_f32_32x32x16_bf16(a1, b1, acc[1][1], 0,0,0);
    }
  }

  const float* bias = mat==0 ? bq : (mat==1 ? bk : bv);
  const float bsc = (mat==0) ? 0.09016844005556021f : 1.0f;   // W pre-scaled; bias scaled here
  float bb_[2];
  #pragma unroll
  for (int ntl=0; ntl<2; ++ntl) bb_[ntl] = bias[cb + nh + ntl*32 + l31] * bsc;

  if (mat <= 1) {
    #pragma unroll
    for (int mt=0; mt<2; ++mt)
      #pragma unroll
      for (int ntl=0; ntl<2; ++ntl)
        #pragma unroll
        for (int r=0; r<16; ++r) {
          int gm = m0 + mh + mt*32 + (r&3) + 8*(r>>2) + 4*h;
          int col = cb + nh + ntl*32 + l31;
          u16 val = f2bf(acc[mt][ntl][r] + bb_[ntl]);
          if (mat == 0) {
            Qb[(size_t)gm*QSTR + col] = val;
          } else {
            int bb2 = gm >> 12, s = gm & (S-1);
            Kt[(size_t)(bb2*128 + (s>>5))*KT_TILE + (s&31)*280 + col] = val;
          }
        }
  } else {
    // V: transpose via LDS, store to Vt tiled [b][t32][e][40]
    __syncthreads();   // T overwrites buf region other waves may still be reading
    u16* T = (u16*)smem;     // [128 e][136] = 34816 B
    #pragma unroll
    for (int mt=0; mt<2; ++mt)
      #pragma unroll
      for (int ntl=0; ntl<2; ++ntl)
        #pragma unroll
        for (int r=0; r<16; ++r) {
          int e_loc = nh + ntl*32 + l31;
          int m_loc = mh + mt*32 + (r&3) + 8*(r>>2) + 4*h;
          T[(size_t)e_loc*136 + m_loc] = f2bf(acc[mt][ntl][r] + bb_[ntl]);
        }
    __syncthreads();
    int e_loc = tid >> 1, shalf = (tid & 1)*64;
    int e = cb + e_loc;
    #pragma unroll
    for (int g2 = 0; g2 < 2; ++g2) {
      int gm = m0 + shalf + g2*32;
      int bb2 = gm >> 12, s = gm & (S-1);
      u16* dst = Vt + (size_t)(bb2*128 + (s>>5))*VT_TILE + (size_t)e*40;
      const u16* src = T + (size_t)e_loc*136 + shalf + g2*32;
      #pragma unroll
      for (int k2=0;k2<4;++k2) *(uint4*)(dst + k2*8) = *(const uint4*)(src + k2*8);
    }
  }
}

// ---------------- attention: QBLK=256, 8 waves, 1 block/CU (halved staging DMA) ------------
// [Structure FROZEN at R11: 78.8us. R5/R8 showed any +16-reg change spills; changes must be
// register-neutral. This round: permlane32_swap with CORRECTED operand order.]
__global__ __launch_bounds__(512, 2) void msp_attn(
    const u16* __restrict__ Qb, const u16* __restrict__ Kt,
    const u16* __restrict__ Vt, float* __restrict__ out,
    float* __restrict__ P1, float* __restrict__ P23,
    float* __restrict__ Lacc)
{
  __shared__ __align__(16) unsigned char smem[77824];  // K dbuf 2x18432 | V dbuf 2x20480

  const int tid = threadIdx.x;
  const int w = tid >> 6, lane = tid & 63;
  const int l31 = lane & 31, h = lane >> 5;

  // XCD-swizzled decode over 256 blocks: 16 qt-blocks sharing (b,tq) land on one XCD
  const int xg = blockIdx.x;
  const int xcd = xg & 7, j = xg >> 3;         // j in 0..31
  const int c = xcd*2 + (j & 1);               // (b,tq) index 0..15
  const int qt = j >> 1;                       // 0..15
  const int b = c >> 2, tq = c & 3;
  const int q0 = qt * 256;
  const int qw = q0 + w*32;

  // Q fragments (B-operand): lane holds Q[qw+l31][16*s2 + 8h + j]
  bf16x8 qf[17];
  {
    const u16* qp = Qb + ((size_t)b*S + qw + l31)*QSTR + h*8;
    #pragma unroll
    for (int s2=0; s2<17; ++s2) qf[s2] = *(const bf16x8*)(qp + s2*16);
  }

  const int tIdx0 = b*128 + tq*32;

  f32x16 oacc[8];
  #pragma unroll
  for (int e=0;e<8;++e)
    #pragma unroll
    for (int i=0;i<16;++i) oacc[e][i] = 0.f;
  float l_acc = 0.f;

  { // prologue: K[0] -> k0
    const u16* kg = Kt + (size_t)tIdx0*KT_TILE;
    u16* kl = (u16*)smem;
    #pragma unroll
    for (int i = w; i < 18; i += 8) gl_lds16(kg + i*512 + lane*8, kl + i*512);
  }

  bf16x8 pf[2];   // carried P^T fragments (softmax computed pre-barrier)

  { // peeled it = 0: stage K[1]->k1 + V[0]->v0; QK[0] from k0; softmax[0] pre-barrier
    __syncthreads();
    const u16* kg = Kt + (size_t)(tIdx0 + 1)*KT_TILE;
    u16* kl = (u16*)(smem + 18432);
    #pragma unroll
    for (int i = w; i < 18; i += 8) gl_lds16(kg + i*512 + lane*8, kl + i*512);
    const u16* vg = Vt + (size_t)tIdx0*VT_TILE;
    u16* vl = (u16*)(smem + 36864);
    #pragma unroll
    for (int i = w; i < 20; i += 8) gl_lds16(vg + i*512 + lane*8, vl + i*512);

    const u16* Kp = (const u16*)smem + (size_t)l31*280 + h*8;
    f32x16 sa;
    #pragma unroll
    for (int i=0;i<16;++i) sa[i] = 0.f;
    __builtin_amdgcn_s_setprio(1);
    #pragma unroll
    for (int s2 = 0; s2 < 17; ++s2) {
      bf16x8 kf = *(const bf16x8*)(Kp + s2*16);
      sa = __builtin_amdgcn_mfma_f32_32x32x16_bf16(kf, qf[s2], sa, 0,0,0);
    }
    __builtin_amdgcn_s_setprio(0);
    softmax_pf(sa, h, l_acc, pf);      // pre-barrier: overlaps DMA drain
  }

  for (int it = 1; it < 32; ++it) {
    const int p = it & 1;
    __syncthreads();            // drains K[it] (-> k[p]) and V[it-1] (-> v[p^1])

    if (it < 31) {              // stage K[it+1] -> k[p^1]
      const u16* kg = Kt + (size_t)(tIdx0 + it + 1)*KT_TILE;
      u16* kl = (u16*)(smem + (p^1)*18432);
      #pragma unroll
      for (int i = w; i < 18; i += 8) gl_lds16(kg + i*512 + lane*8, kl + i*512);
    }
    {                           // stage V[it] -> v[p]
      const u16* vg = Vt + (size_t)(tIdx0 + it)*VT_TILE;
      u16* vl = (u16*)(smem + 36864 + p*20480);
      #pragma unroll
      for (int i = w; i < 20; i += 8) gl_lds16(vg + i*512 + lane*8, vl + i*512);
    }

    // QK[it] (chain sa) interleaved with PV[it-1] (carried pf, independent accumulators)
    const u16* Kp = (const u16*)(smem + p*18432) + (size_t)l31*280 + h*8;
    const u16* Vp = (const u16*)(smem + 36864 + (p^1)*20480) + (size_t)l31*40 + h*8;
    f32x16 sa;
    #pragma unroll
    for (int i=0;i<16;++i) sa[i] = 0.f;
    __builtin_amdgcn_s_setprio(1);
    #pragma unroll
    for (int s2 = 0; s2 < 17; ++s2) {
      bf16x8 kf = *(const bf16x8*)(Kp + s2*16);
      sa = __builtin_amdgcn_mfma_f32_32x32x16_bf16(kf, qf[s2], sa, 0,0,0);
      if (s2 < 16) {
        const u16* vb = Vp + (s2>>1)*(32*40) + (s2&1)*16;
        oacc[s2>>1] = __builtin_amdgcn_mfma_f32_32x32x16_bf16(*(const bf16x8*)vb, pf[s2&1], oacc[s2>>1], 0,0,0);
      }
    }
    __builtin_amdgcn_s_setprio(0);

    // softmax[it] pre-barrier -> new pf (old pf consumed by the PV MFMAs above)
    softmax_pf(sa, h, l_acc, pf);
  }

  // tail: l-reduce, then PV[31] from v[1] with the carried pf
  float l_tot = l_acc + __shfl_xor(l_acc, 32, 64);
  if (h == 0) unsafeAtomicAdd(&Lacc[(size_t)b*S + qw + l31], l_tot);

  __syncthreads();              // drain V[31] (staged during it=31 into v[1])
  {
    const u16* Vp = (const u16*)(smem + 36864 + 20480) + (size_t)l31*40 + h*8;
    __builtin_amdgcn_s_setprio(1);
    #pragma unroll
    for (int et = 0; et < 8; ++et) {
      const u16* vb = Vp + et*32*40;
      oacc[et] = __builtin_amdgcn_mfma_f32_32x32x16_bf16(*(const bf16x8*)(vb),      pf[0], oacc[et], 0,0,0);
      oacc[et] = __builtin_amdgcn_mfma_f32_32x32x16_bf16(*(const bf16x8*)(vb + 16), pf[1], oacc[et], 0,0,0);
    }
    __builtin_amdgcn_s_setprio(0);
  }

  // transpose O^T -> O via LDS: 4 rounds, 2 waves each (A/B buffers), STREAMING float4
  // stores; unique writer per (tq, b, q-row) -> no atomics
  float* dst = (tq == 0) ? (out + (size_t)b*S*D)
             : (tq == 1) ? (P1 + (size_t)b*S*D)
                         : (P23 + ((size_t)(tq-2)*4 + b)*S*D);
  float* OflA = (float*)smem;            // [32 q][260]
  float* OflB = (float*)smem + 8320;     // second buffer
  for (int rr = 0; rr < 4; ++rr) {
    __syncthreads();
    if ((w >> 1) == rr) {
      float* Of = (w & 1) ? OflB : OflA;
      #pragma unroll
      for (int et=0; et<8; ++et)
        #pragma unroll
        for (int g=0; g<4; ++g) {
          float4 v4 = { oacc[et][4*g+0], oacc[et][4*g+1], oacc[et][4*g+2], oacc[et][4*g+3] };
          *(float4*)&Of[(size_t)l31*260 + et*32 + 8*g + 4*h] = v4;
        }
    }
    __syncthreads();
    #pragma unroll
    for (int hf = 0; hf < 2; ++hf) {
      const float* Of = hf ? OflB : OflA;
      float* obase = dst + (size_t)(q0 + rr*64 + hf*32)*D;
      #pragma unroll
      for (int q2 = 0; q2 < 4; ++q2) {
        int q = q2*8 + (tid>>6);
        int e4 = (tid & 63)*4;
        *(float4*)(obase + (size_t)q*D + e4) = *(const float4*)&Of[(size_t)q*260 + e4];
      }
    }
  }
}

// ---------------- fused 4-way partial sum + normalize ----------------
__global__ __launch_bounds__(256) void msp_norm(
    float* __restrict__ out, const float* __restrict__ P1,
    const float* __restrict__ P23, const float* __restrict__ L)
{
  constexpr size_t PSZ = (size_t)4*S*D;   // floats per partial set (4 batches)
  int idx = blockIdx.x*256 + threadIdx.x;
  int row = idx >> 6, e0 = (idx & 63)*4;
  size_t off = (size_t)row*256 + e0;
  float inv = 1.0f / L[row];
  float4 v  = *(const float4*)(out + off);
  float4 a  = *(const float4*)(P1  + off);
  float4 b2 = *(const float4*)(P23 + off);
  float4 c2 = *(const float4*)(P23 + PSZ + off);
  v.x = (v.x + a.x + b2.x + c2.x) * inv;
  v.y = (v.y + a.y + b2.y + c2.y) * inv;
  v.z = (v.z + a.z + b2.z + c2.z) * inv;
  v.w = (v.w + a.w + b2.w + c2.w) * inv;
  *(float4*)(out + off) = v;
}

extern "C" void kernel_launch(void* const* d_in, const int* in_sizes, int n_in,
                              void* d_out, int out_size, void* d_ws, size_t ws_size,
                              hipStream_t stream) {
  const float* x    = (const float*)d_in[0];
  const float* Wq   = (const float*)d_in[1];
  const float* bq   = (const float*)d_in[2];
  const float* Wk   = (const float*)d_in[3];
  const float* bk   = (const float*)d_in[4];
  const float* Wv   = (const float*)d_in[5];
  const float* bv   = (const float*)d_in[6];
  const float* beta = (const float*)d_in[7];
  float* out = (float*)d_out;

  char* w = (char*)d_ws;
  u16* xc = (u16*)w;                                // 8.4 MB used (K=256, hi only)
  float* P1 = (float*)w;                            // overlays xc region (dead after proj)
  w += (size_t)16384*512*2;                         // 16.8 MB reserved (P1 needs it)
  u16* Wc = (u16*)w;  w += (size_t)768*512*2;       // 0.39 MB used of 0.79 reservation
  u16* Qb = (u16*)w;  w += (size_t)16384*QSTR*2;    // 8.9 MB
  u16* Kt = (u16*)w;  w += (size_t)512*KT_TILE*2;   // 9.2 MB (Vt must follow: junk-tail reads)
  u16* Vt = (u16*)w;  w += (size_t)512*VT_TILE*2;   // 10.5 MB
  float* Lacc = (float*)w; w += (size_t)16384*4;    // 64 KB
  float* P23 = (float*)w;                           // 2 x 16.8 MB

  msp_prep<<<2209, 256, 0, stream>>>(x, Wq, Wk, Wv, beta, xc, Wc, Qb, Kt, Lacc);
  msp_proj<<<dim3(128, 6), 256, 0, stream>>>(xc, Wc, bq, bk, bv, Qb, Kt, Vt);
  msp_attn<<<256, 512, 0, stream>>>(Qb, Kt, Vt, out, P1, P23, Lacc);
  msp_norm<<<4096, 256, 0, stream>>>(out, P1, P23, Lacc);
}